// Round 6
// baseline (3706.901 us; speedup 1.0000x reference)
//
#include <hip/hip_runtime.h>
#include <math.h>

// ---------------- problem constants ----------------
constexpr int CB = 8, CT = 4096, CP = 4, CD = 512, CV = 256;
constexpr int CN = 1024, CK = 16, CH = 8, CHD = 64;
constexpr int ROWS = CB * CN;     // 8192
constexpr int TROWS = CB * CT;    // 32768
constexpr float CEPS = 1e-5f;
constexpr size_t PN = (size_t)ROWS * CD;   // 4,194,304 (one pair-plane)

// ---------------- workspace layout (floats) ----------------
constexpr size_t OFF_LOCAL = 0;                                    // 16,777,216 fp32 local
constexpr size_t OFF_HP    = OFF_LOCAL + (size_t)ROWS * CP * CD;   //  4,194,304 h pair
constexpr size_t OFF_X4    = OFF_HP    + PN;                       // 20,971,520 fused5/scores/gi+ghn/arqkv/final
constexpr size_t OFF_MS    = OFF_X4    + (size_t)ROWS * 2560;      //  4,194,304 msgs pair / broad fp32
constexpr size_t OFF_A     = OFF_MS    + PN;                       //  4,194,304 pair A
constexpr size_t OFF_B     = OFF_A     + PN;                       //  4,194,304 pair B
constexpr size_t OFF_BIAS  = OFF_B     + PN;                       //      4,096
constexpr size_t OFF_WT    = OFF_BIAS  + 4096;                     //  7,471,104
// end = 62,011,008 floats = 236.6 MiB

constexpr size_t TOT_W    = 7471104;
constexpr size_t T_GRU_IH = 0;                     // 1536x512
constexpr size_t T_GRU_HH = 786432;                // 1536x512
constexpr size_t T_SUMM   = 1572864;               // 512x512
constexpr size_t T_FUSE   = 1835008;               // 2560x512 (msg1a|msg1b|qw|kw|vw)
constexpr size_t T_MSG2   = 3145728;               // 512x512
constexpr size_t T_OW     = 3407872;               // 512x512
constexpr size_t T_GCAB   = 3670016;               // 1536x1024 ([gc_top|gc_bot] along K)
constexpr size_t T_GC_HH  = 5242880;               // 1536x512
constexpr size_t T_AR_QKV = 6029312;               // 1536x512
constexpr size_t T_AR_OUT = 6815744;               // 512x512
constexpr size_t T_BROAD  = 7077888;               // 512x512
constexpr size_t T_HEAD   = 7340032;               // 256x512

// GEMM flags
constexpr int F_ACC_F32  = 1;
constexpr int F_ACC_PAIR = 2;
constexpr int F_WR_F32   = 4;
constexpr int F_WR_PAIR  = 8;
constexpr int F_TRI      = 16;
constexpr int F_SPLIT    = 32;   // col<1024: accumulate into Cf; col>=1024: write Cf2

// ---------------- device helpers ----------------
typedef __attribute__((ext_vector_type(8))) short short8;
typedef __attribute__((ext_vector_type(4))) float f32x4;
typedef __attribute__((ext_vector_type(16))) float f32x16;

__device__ __forceinline__ float sigm(float x) { return 1.f / (1.f + expf(-x)); }
__device__ __forceinline__ float geluf(float x) {
  return 0.5f * x * (1.f + erff(x * 0.7071067811865475f));
}
__device__ __forceinline__ unsigned short bf_hi(float x) {
  const unsigned u = __float_as_uint(x);
  return (unsigned short)((u + 0x7FFFu + ((u >> 16) & 1u)) >> 16);
}
__device__ __forceinline__ float bf_f(unsigned short h) {
  return __uint_as_float((unsigned)h << 16);
}
__device__ __forceinline__ void split_store(float v, unsigned short* ph, unsigned short* pl) {
  const unsigned short h = bf_hi(v);
  *ph = h; *pl = bf_hi(v - bf_f(h));
}
__device__ __forceinline__ float blk_sum(float v, float* red) {
#pragma unroll
  for (int o = 32; o > 0; o >>= 1) v += __shfl_down(v, o, 64);
  const int wv = threadIdx.x >> 6, ln = threadIdx.x & 63;
  __syncthreads();
  if (ln == 0) red[wv] = v;
  __syncthreads();
  return red[0] + red[1] + red[2] + red[3];
}

// bijective XCD swizzle (m204): dispatcher assigns consecutive flat block ids
// round-robin across 8 XCDs; remap so each XCD owns a CONTIGUOUS chunk of the
// work-id space -> neighboring tiles (sharing A/B panels / K-V groups / batch
// slices) hit the same L2.
__device__ __forceinline__ int xcd_swz(int i, int n) {
  if (n < 8) return i;
  const int q = n >> 3, r = n & 7;
  const int xcd = i & 7, slot = i >> 3;
  return (xcd < r ? xcd * (q + 1) : r * (q + 1) + (xcd - r) * q) + slot;
}

// ---------------- transpose + bf16 split (weights) ----------------
__global__ __launch_bounds__(256) void transpose_split(const float* __restrict__ in,
                                                       unsigned short* __restrict__ oh,
                                                       unsigned short* __restrict__ ol,
                                                       int K, int N, int ldk, int ko)
{
  __shared__ float tile[32][33];
  const int n0 = blockIdx.x * 32, k0 = blockIdx.y * 32;
  const int tx = threadIdx.x & 31, ty = threadIdx.x >> 5;
#pragma unroll
  for (int i = 0; i < 32; i += 8)
    tile[ty + i][tx] = in[(size_t)(k0 + ty + i) * N + n0 + tx];
  __syncthreads();
#pragma unroll
  for (int i = 0; i < 32; i += 8) {
    const float v = tile[tx][ty + i];
    const unsigned short h = bf_hi(v);
    const size_t o = (size_t)(n0 + ty + i) * ldk + ko + k0 + tx;
    oh[o] = h;
    ol[o] = bf_hi(v - bf_f(h));
  }
}

__global__ void concat_bias5(const float* __restrict__ b1, const float* __restrict__ qb,
                             const float* __restrict__ kb, const float* __restrict__ vb,
                             float* __restrict__ o)
{
  const int i = blockIdx.x * 256 + threadIdx.x;   // 2560
  float v;
  if (i < 512) v = b1[i];
  else if (i < 1024) v = 0.f;
  else if (i < 1536) v = qb[i - 1024];
  else if (i < 2048) v = kb[i - 1536];
  else v = vb[i - 2048];
  o[i] = v;
}

// ---------------- bf16 MFMA GEMM (128x128 tile, 32x32x16 MFMA) ----------
// Wave tile 64x64 = 2x2 sub-tiles of 32x32. Same LDS staging as before; per
// k-step operand reads are unchanged (12x ds_read_b128/wave) but MFMA
// instruction count halves and the 32x32 pipe runs ~4096 FLOP/cy vs 3277.
// A/B frag: row/col = lane&31, k = (lane>>5)*8 + e (8 contiguous).
// C/D frag (HW-verified m74/m101): col = lane&31,
//   row = (reg&3) + 8*(reg>>2) + 4*(lane>>5).
// P3=true : 3-product (ah*bh + ah*bl + al*bh) — fp32-grade both sides (scores).
// P3=false: 2-product (ah*bh + al*bh) — A fp32-grade, B truncated to bf16.
template <bool P3>
__global__ __launch_bounds__(256, 2) void gemm_bf3(
    const unsigned short* __restrict__ AH, const unsigned short* __restrict__ AL,
    const unsigned short* __restrict__ A2H, const unsigned short* __restrict__ A2L,
    int K1, int lda,
    const unsigned short* __restrict__ BH, const unsigned short* __restrict__ BL, int ldb,
    const float* __restrict__ bias, float scale,
    float* __restrict__ Cf, int ldc, float* __restrict__ Cf2,
    unsigned short* __restrict__ CHp, unsigned short* __restrict__ CLp, int ldcp,
    int K, int flags, long long sA, long long sB, long long sC)
{
  AH += (size_t)blockIdx.z * sA; AL += (size_t)blockIdx.z * sA;
  BH += (size_t)blockIdx.z * sB; BL += (size_t)blockIdx.z * sB;
  if (Cf) Cf += (size_t)blockIdx.z * sC;
  int bm, bn;
  if (flags & F_TRI) {
    int t = xcd_swz(blockIdx.x, gridDim.x), i = 0, acc0 = 0;
    while (acc0 + i + 1 <= t) { ++i; acc0 += i; }
    bm = i << 7; bn = (t - acc0) << 7;
  } else {
    const int w = xcd_swz(blockIdx.x + gridDim.x * blockIdx.y, gridDim.x * gridDim.y);
    bm = (w / gridDim.x) << 7; bn = (w % gridDim.x) << 7;
  }
  __shared__ __align__(16) unsigned short AsH[128][40];
  __shared__ __align__(16) unsigned short AsL[128][40];
  __shared__ __align__(16) unsigned short BsH[128][40];
  __shared__ __align__(16) unsigned short BsL[P3 ? 128 : 1][40];
  const int tid = threadIdx.x;
  const int lane = tid & 63, wave = tid >> 6;
  const int wm = (wave & 1) << 6, wn = (wave >> 1) << 6;
  const int l31 = lane & 31, half = lane >> 5;
  const int sr = tid >> 1, sc = (tid & 1) << 4;
  f32x16 acc[2][2];
#pragma unroll
  for (int i = 0; i < 2; ++i)
#pragma unroll
    for (int j = 0; j < 2; ++j)
#pragma unroll
      for (int e = 0; e < 16; ++e) acc[i][j][e] = 0.f;

  for (int k0 = 0; k0 < K; k0 += 32) {
    const int kc = k0 + sc;
    const unsigned short *pAH, *pAL;
    if (kc < K1) {
      pAH = AH + (size_t)(bm + sr) * lda + kc;
      pAL = AL + (size_t)(bm + sr) * lda + kc;
    } else {
      pAH = A2H + (size_t)(bm + sr) * lda + (kc - K1);
      pAL = A2L + (size_t)(bm + sr) * lda + (kc - K1);
    }
    const unsigned short* pBH = BH + (size_t)(bn + sr) * ldb + kc;
    *(uint4*)&AsH[sr][sc]     = *(const uint4*)pAH;
    *(uint4*)&AsH[sr][sc + 8] = *(const uint4*)(pAH + 8);
    *(uint4*)&AsL[sr][sc]     = *(const uint4*)pAL;
    *(uint4*)&AsL[sr][sc + 8] = *(const uint4*)(pAL + 8);
    *(uint4*)&BsH[sr][sc]     = *(const uint4*)pBH;
    *(uint4*)&BsH[sr][sc + 8] = *(const uint4*)(pBH + 8);
    if (P3) {
      const unsigned short* pBL = BL + (size_t)(bn + sr) * ldb + kc;
      *(uint4*)&BsL[sr][sc]     = *(const uint4*)pBL;
      *(uint4*)&BsL[sr][sc + 8] = *(const uint4*)(pBL + 8);
    }
    __syncthreads();
    // operand fragments: k = ks*16 + half*8 .. +7
    short8 bh[2][2], bl[2][2];
#pragma unroll
    for (int ni = 0; ni < 2; ++ni)
#pragma unroll
      for (int ks = 0; ks < 2; ++ks) {
        bh[ni][ks] = *(const short8*)&BsH[wn + ni * 32 + l31][ks * 16 + half * 8];
        if (P3) bl[ni][ks] = *(const short8*)&BsL[wn + ni * 32 + l31][ks * 16 + half * 8];
      }
#pragma unroll
    for (int mi = 0; mi < 2; ++mi) {
      short8 ah[2], al[2];
#pragma unroll
      for (int ks = 0; ks < 2; ++ks) {
        ah[ks] = *(const short8*)&AsH[wm + mi * 32 + l31][ks * 16 + half * 8];
        al[ks] = *(const short8*)&AsL[wm + mi * 32 + l31][ks * 16 + half * 8];
      }
#pragma unroll
      for (int ni = 0; ni < 2; ++ni)
#pragma unroll
        for (int ks = 0; ks < 2; ++ks) {
          acc[mi][ni] = __builtin_amdgcn_mfma_f32_32x32x16_bf16(ah[ks], bh[ni][ks], acc[mi][ni], 0, 0, 0);
          acc[mi][ni] = __builtin_amdgcn_mfma_f32_32x32x16_bf16(al[ks], bh[ni][ks], acc[mi][ni], 0, 0, 0);
          if (P3)
            acc[mi][ni] = __builtin_amdgcn_mfma_f32_32x32x16_bf16(ah[ks], bl[ni][ks], acc[mi][ni], 0, 0, 0);
        }
    }
    __syncthreads();
  }
#pragma unroll
  for (int mi = 0; mi < 2; ++mi) {
#pragma unroll
    for (int ni = 0; ni < 2; ++ni) {
      const int col = bn + wn + ni * 32 + l31;
      const float bv = bias ? bias[col] : 0.f;
#pragma unroll
      for (int reg = 0; reg < 16; ++reg) {
        const int row = bm + wm + mi * 32 + (reg & 3) + ((reg >> 2) << 3) + (half << 2);
        float o = acc[mi][ni][reg] * scale + bv;
        if (flags & F_SPLIT) {
          if (col < 1024) {
            float* p = Cf + (size_t)row * ldc + col;
            *p = o + *p;
          } else {
            Cf2[(size_t)row * 512 + (col - 1024)] = o;
          }
        } else {
          if (flags & F_ACC_F32) o += Cf[(size_t)row * ldc + col];
          if (flags & F_ACC_PAIR) {
            const size_t ip = (size_t)row * ldcp + col;
            o += bf_f(CHp[ip]) + bf_f(CLp[ip]);
          }
          if (flags & F_WR_F32) Cf[(size_t)row * ldc + col] = o;
          if (flags & F_WR_PAIR) {
            const size_t ip = (size_t)row * ldcp + col;
            split_store(o, &CHp[ip], &CLp[ip]);
          }
        }
      }
    }
  }
}

// ---------------- small-tile variant: 64x128, 2-product ----------
__global__ __launch_bounds__(256, 3) void gemm_bf3s(
    const unsigned short* __restrict__ AH, const unsigned short* __restrict__ AL, int lda,
    const unsigned short* __restrict__ BH, int ldb,
    const float* __restrict__ bias,
    float* __restrict__ Cf, int ldc,
    unsigned short* __restrict__ CHp, unsigned short* __restrict__ CLp, int ldcp,
    int K, int flags)
{
  const int w = xcd_swz(blockIdx.x + gridDim.x * blockIdx.y, gridDim.x * gridDim.y);
  const int bm = (w / gridDim.x) << 6, bn = (w % gridDim.x) << 7;
  __shared__ __align__(16) unsigned short AsH[64][40];
  __shared__ __align__(16) unsigned short AsL[64][40];
  __shared__ __align__(16) unsigned short BsH[128][40];
  const int tid = threadIdx.x;
  const int lane = tid & 63, wave = tid >> 6;
  const int wm = (wave & 1) << 5, wn = (wave >> 1) << 6;
  const int r16 = lane & 15, quad = lane >> 4;
  const int sar = tid >> 2, sac = (tid & 3) << 3;
  const int sbr = tid >> 1, sbc = (tid & 1) << 4;
  const f32x4 zero = {0.f, 0.f, 0.f, 0.f};
  f32x4 acc[2][4];
#pragma unroll
  for (int i = 0; i < 2; ++i)
#pragma unroll
    for (int j = 0; j < 4; ++j) acc[i][j] = zero;

  for (int k0 = 0; k0 < K; k0 += 32) {
    const unsigned short* pAH = AH + (size_t)(bm + sar) * lda + k0 + sac;
    const unsigned short* pAL = AL + (size_t)(bm + sar) * lda + k0 + sac;
    const unsigned short* pBH = BH + (size_t)(bn + sbr) * ldb + k0 + sbc;
    *(uint4*)&AsH[sar][sac] = *(const uint4*)pAH;
    *(uint4*)&AsL[sar][sac] = *(const uint4*)pAL;
    *(uint4*)&BsH[sbr][sbc]     = *(const uint4*)pBH;
    *(uint4*)&BsH[sbr][sbc + 8] = *(const uint4*)(pBH + 8);
    __syncthreads();
    short8 bh[4];
#pragma unroll
    for (int ni = 0; ni < 4; ++ni)
      bh[ni] = *(const short8*)&BsH[wn + ni * 16 + r16][quad * 8];
#pragma unroll
    for (int mi = 0; mi < 2; ++mi) {
      const short8 ah = *(const short8*)&AsH[wm + mi * 16 + r16][quad * 8];
      const short8 al = *(const short8*)&AsL[wm + mi * 16 + r16][quad * 8];
#pragma unroll
      for (int ni = 0; ni < 4; ++ni) {
        acc[mi][ni] = __builtin_amdgcn_mfma_f32_16x16x32_bf16(ah, bh[ni], acc[mi][ni], 0, 0, 0);
        acc[mi][ni] = __builtin_amdgcn_mfma_f32_16x16x32_bf16(al, bh[ni], acc[mi][ni], 0, 0, 0);
      }
    }
    __syncthreads();
  }
#pragma unroll
  for (int mi = 0; mi < 2; ++mi) {
    const int row0 = bm + wm + mi * 16 + quad * 4;
#pragma unroll
    for (int ni = 0; ni < 4; ++ni) {
      const int col = bn + wn + ni * 16 + r16;
      const float bv = bias ? bias[col] : 0.f;
#pragma unroll
      for (int rg = 0; rg < 4; ++rg) {
        const int row = row0 + rg;
        float o = acc[mi][ni][rg] + bv;
        if (flags & F_ACC_PAIR) {
          const size_t ip = (size_t)row * ldcp + col;
          o += bf_f(CHp[ip]) + bf_f(CLp[ip]);
        }
        if (flags & F_WR_F32) Cf[(size_t)row * ldc + col] = o;
        if (flags & F_WR_PAIR) {
          const size_t ip = (size_t)row * ldcp + col;
          split_store(o, &CHp[ip], &CLp[ip]);
        }
      }
    }
  }
}

// ---------------- small kernels ----------------
__global__ void zero_k(float* __restrict__ p) {
  p[(size_t)blockIdx.x * 256 + threadIdx.x] = 0.f;
}

__global__ void embed_p(const int* __restrict__ x, const float* __restrict__ emb,
                        const float* __restrict__ pos,
                        unsigned short* __restrict__ oh, unsigned short* __restrict__ ol, int t)
{
  const int i = blockIdx.x * 256 + threadIdx.x;
  const int r = i >> 9, d = i & 511;
  const int b = r >> 10, n = r & (CN - 1);
  const int tok = x[b * CT + n * CP + t];
  const float v = emb[(size_t)tok * CD + d] + pos[t * CD + d];
  split_store(v, &oh[i], &ol[i]);
}

__global__ void gru_point_p(const float* __restrict__ gi, const float* __restrict__ ghn,
                            unsigned short* __restrict__ hH, unsigned short* __restrict__ hL,
                            float* __restrict__ hs, int t)
{
  const int i = blockIdx.x * 256 + threadIdx.x;
  const int r = i >> 9, d = i & 511;
  const size_t gb = (size_t)r * (3 * CD) + d;
  const float sr_ = gi[gb], sz = gi[gb + CD], inn = gi[gb + 2 * CD];
  const float hn = ghn[i];
  const float hp = bf_f(hH[i]) + bf_f(hL[i]);
  const float rr = sigm(sr_), zz = sigm(sz);
  const float nn = tanhf(inn + rr * hn);
  const float hv = (1.f - zz) * nn + zz * hp;
  split_store(hv, &hH[i], &hL[i]);
  hs[(size_t)r * (CP * CD) + (size_t)t * CD + d] = hv;
}

__global__ __launch_bounds__(256) void ln_rows(const float* __restrict__ in, float* __restrict__ out,
                                               const float* __restrict__ g, const float* __restrict__ b)
{
  const int r = blockIdx.x, t = threadIdx.x;
  __shared__ float red[4];
  const float* ip = in + (size_t)r * CD;
  const float v0 = ip[t], v1 = ip[t + 256];
  const float mu = blk_sum(v0 + v1, red) * (1.f / CD);
  const float d0 = v0 - mu, d1 = v1 - mu;
  const float var = blk_sum(d0 * d0 + d1 * d1, red) * (1.f / CD);
  const float inv = rsqrtf(var + CEPS);
  float* op = out + (size_t)r * CD;
  op[t] = d0 * inv * g[t] + b[t];
  op[t + 256] = d1 * inv * g[t + 256] + b[t + 256];
}

__global__ void mean_pool_p(const float* __restrict__ local,
                            unsigned short* __restrict__ oh, unsigned short* __restrict__ ol)
{
  const int i = blockIdx.x * 256 + threadIdx.x;
  const int r = i >> 9, d = i & 511;
  const float* p = local + (size_t)r * (CP * CD) + d;
  split_store(0.25f * (p[0] + p[CD] + p[2 * CD] + p[3 * CD]), &oh[i], &ol[i]);
}

__global__ void msg_gelu_p(const float* __restrict__ X4,
                           unsigned short* __restrict__ oh, unsigned short* __restrict__ ol)
{
  const int i = blockIdx.x * 256 + threadIdx.x;
  const int r = i >> 9, d = i & 511;
  const int n = r & (CN - 1);
  const float pv = X4[(size_t)r * 2560 + d];
  float acc = 0.f;
#pragma unroll
  for (int w = 0; w <= 4; ++w) {
    const float xv = pv + ((n >= w) ? X4[(size_t)(r - w) * 2560 + 512 + d] : 0.f);
    acc += geluf(xv);
  }
  split_store(acc * 0.2f, &oh[i], &ol[i]);
}

__global__ void rotary2_p(const float* __restrict__ X4,
                          unsigned short* __restrict__ qh, unsigned short* __restrict__ ql,
                          unsigned short* __restrict__ kh, unsigned short* __restrict__ kl)
{
  const int i = blockIdx.x * 256 + threadIdx.x;   // ROWS*256
  const int r = i >> 8, j = i & 255;
  const int n = r & (CN - 1);
  const float fr = (float)n * expf(-9.210340371976184f * ((float)j * (1.f / 256.f)));
  float s, c;
  sincosf(fr, &s, &c);
  const float* p = X4 + (size_t)r * 2560;
  const size_t o0 = (size_t)r * CD + j, o1 = o0 + 256;
  const float q1 = p[1024 + j], q2 = p[1024 + 256 + j];
  split_store(q1 * c - q2 * s, &qh[o0], &ql[o0]);
  split_store(q2 * c + q1 * s, &qh[o1], &ql[o1]);
  const float k1 = p[1536 + j], k2 = p[1536 + 256 + j];
  split_store(k1 * c - k2 * s, &kh[o0], &kl[o0]);
  split_store(k2 * c + k1 * s, &kh[o1], &kl[o1]);
}

// ---------------- fused top-K + softmax + gather ----------------
// One WAVE per row (4 rows per block): single-phase selection -> serial
// reduce-chain halves vs the 2-phase block version; no __syncthreads at all.
// Batch-per-XCD swizzle keeps each batch's 2 MB V-slice L2-resident.
__global__ __launch_bounds__(256) void topk_attn(const float* __restrict__ X4,
                                                 unsigned short* __restrict__ ctxH,
                                                 unsigned short* __restrict__ ctxL)
{
  const int g = xcd_swz(blockIdx.x, gridDim.x);
  const int wave = threadIdx.x >> 6, lane = threadIdx.x & 63;
  const int r = g * 4 + wave;
  const int b = r >> 10, n = r & (CN - 1);
  const float* row = X4 + (size_t)r * 2560;
  __shared__ float p16s[4][CK];
  __shared__ int   i16s[4][CK];

  unsigned long long key[16];
#pragma unroll
  for (int q = 0; q < 16; ++q) {
    const int m = q * 64 + lane;
    const float v = (m <= n) ? row[m] : -INFINITY;
    unsigned u = __float_as_uint(v);
    u = (u & 0x80000000u) ? ~u : (u | 0x80000000u);
    key[q] = ((unsigned long long)u << 32) | (unsigned)(CN - 1 - m);
  }
  // per-lane max via tree (ILP-friendly)
  unsigned long long lane_best;
  {
    unsigned long long t[8];
#pragma unroll
    for (int i = 0; i < 8; ++i) t[i] = key[i] > key[i + 8] ? key[i] : key[i + 8];
#pragma unroll
    for (int i = 0; i < 4; ++i) t[i] = t[i] > t[i + 4] ? t[i] : t[i + 4];
    t[0] = t[0] > t[2] ? t[0] : t[2];
    t[1] = t[1] > t[3] ? t[1] : t[3];
    lane_best = t[0] > t[1] ? t[0] : t[1];
  }
  unsigned long long mine = 0ull;
#pragma unroll
  for (int it = 0; it < CK; ++it) {
    unsigned long long best = lane_best;
#pragma unroll
    for (int o = 32; o > 0; o >>= 1) {
      const unsigned long long o2 = __shfl_xor(best, o, 64);
      best = best > o2 ? best : o2;
    }
    if (lane == it) mine = best;
    if (lane_best == best) {   // exactly one lane (keys unique via index bits)
#pragma unroll
      for (int q = 0; q < 16; ++q)
        if (key[q] == best) key[q] = 0ull;
      unsigned long long t[8];
#pragma unroll
      for (int i = 0; i < 8; ++i) t[i] = key[i] > key[i + 8] ? key[i] : key[i + 8];
#pragma unroll
      for (int i = 0; i < 4; ++i) t[i] = t[i] > t[i + 4] ? t[i] : t[i + 4];
      t[0] = t[0] > t[2] ? t[0] : t[2];
      t[1] = t[1] > t[3] ? t[1] : t[3];
      lane_best = t[0] > t[1] ? t[0] : t[1];
    }
  }
  // lanes 0..15 hold the sorted top-16; softmax among them (wave-local)
  unsigned u = (unsigned)(mine >> 32);
  u = (u & 0x80000000u) ? (u & 0x7FFFFFFFu) : ~u;
  const float val = __uint_as_float(u);
  const int idx = CN - 1 - (int)(mine & 0xFFFFFFFFu);
  const float mx = __shfl(val, 0, 64);   // it=0 winner is the global max
  float e = 0.f;
  if (lane < CK && val != -INFINITY) e = expf(val - mx);
  float sum = e;
#pragma unroll
  for (int o = 8; o > 0; o >>= 1) sum += __shfl_xor(sum, o, 64);
  if (lane < CK) {
    p16s[wave][lane] = e / sum;
    i16s[wave][lane] = idx;
  }
  // wave-local LDS RAW: wave executes in lockstep, DS ops in order — no barrier
  float pr[CK];
  int   ro[CK];
  const int vb = b << 10;
#pragma unroll
  for (int q = 0; q < CK; ++q) {
    pr[q] = p16s[wave][q];
    ro[q] = (vb + i16s[wave][q]) * 2560 + 2048;
  }
#pragma unroll
  for (int pass = 0; pass < 8; ++pass) {
    const int d = pass * 64 + lane;
    float a = 0.f;
#pragma unroll
    for (int q = 0; q < CK; ++q)
      a += pr[q] * X4[(size_t)ro[q] + d];
    split_store(a, &ctxH[(size_t)r * CD + d], &ctxL[(size_t)r * CD + d]);
  }
}

// gru + msg-LN; optionally also ar-LN of the new h -> (aH,aL)
__global__ __launch_bounds__(256) void gru_ln_p(const float* __restrict__ gi, const float* __restrict__ ghn,
                                                unsigned short* __restrict__ hH, unsigned short* __restrict__ hL,
                                                const float* __restrict__ g, const float* __restrict__ b,
                                                unsigned short* __restrict__ aH, unsigned short* __restrict__ aL,
                                                const float* __restrict__ g2, const float* __restrict__ b2)
{
  const int r = blockIdx.x, t = threadIdx.x;
  __shared__ float red[4];
  float u[2];
#pragma unroll
  for (int q = 0; q < 2; ++q) {
    const int d = t + q * 256;
    const size_t gb = (size_t)r * (3 * CD) + d;
    const float sr_ = gi[gb], sz = gi[gb + CD], inn = gi[gb + 2 * CD];
    const float hn = ghn[(size_t)r * CD + d];
    const size_t hi = (size_t)r * CD + d;
    const float hp = bf_f(hH[hi]) + bf_f(hL[hi]);
    const float rr = sigm(sr_), zz = sigm(sz);
    const float nn = tanhf(inn + rr * hn);
    u[q] = (1.f - zz) * nn + zz * hp;
  }
  const float mu = blk_sum(u[0] + u[1], red) * (1.f / CD);
  const float d0 = u[0] - mu, d1 = u[1] - mu;
  const float var = blk_sum(d0 * d0 + d1 * d1, red) * (1.f / CD);
  const float inv = rsqrtf(var + CEPS);
  const float h0 = d0 * inv * g[t] + b[t];
  const float h1 = d1 * inv * g[t + 256] + b[t + 256];
  split_store(h0, &hH[(size_t)r * CD + t], &hL[(size_t)r * CD + t]);
  split_store(h1, &hH[(size_t)r * CD + t + 256], &hL[(size_t)r * CD + t + 256]);
  if (aH) {
    const float mu2 = blk_sum(h0 + h1, red) * (1.f / CD);
    const float e0 = h0 - mu2, e1 = h1 - mu2;
    const float var2 = blk_sum(e0 * e0 + e1 * e1, red) * (1.f / CD);
    const float inv2 = rsqrtf(var2 + CEPS);
    split_store(e0 * inv2 * g2[t] + b2[t], &aH[(size_t)r * CD + t], &aL[(size_t)r * CD + t]);
    split_store(e1 * inv2 * g2[t + 256] + b2[t + 256],
                &aH[(size_t)r * CD + t + 256], &aL[(size_t)r * CD + t + 256]);
  }
}

// ---------------- MFMA flash attention, pair I/O ----------------
// 1D grid + XCD swizzle (T1): the 16 qt-blocks sharing one (head,b)'s K/V stay
// on one XCD's L2. K/V for tile j+1 prefetched into registers during tile j's
// compute (T14 async-stage split) so HBM/L2 latency hides under MFMA+softmax.
constexpr int FP = 72;
__global__ __launch_bounds__(256, 2) void flash_attn_p(const unsigned short* __restrict__ qkvH,
                                                       const unsigned short* __restrict__ qkvL,
                                                       unsigned short* __restrict__ outH,
                                                       unsigned short* __restrict__ outL)
{
  __shared__ __align__(16) unsigned short Qh[64 * FP], Ql[64 * FP];
  __shared__ __align__(16) unsigned short Kh[64 * FP], Kl[64 * FP];
  __shared__ __align__(16) unsigned short Vth[64 * FP], Vtl[64 * FP];
  __shared__ __align__(16) unsigned short Pm[64 * FP];
  const int w = xcd_swz(blockIdx.x, gridDim.x);
  const int qt = w & 15, head = (w >> 4) & 7, b = w >> 7;
  const int tid = threadIdx.x;
  const int lane = tid & 63, wave = tid >> 6;
  const int r16 = lane & 15, quad = lane >> 4;
  const size_t base = (size_t)b * CN * (3 * CD) + head * CHD;

  {
    const int r = tid >> 2, c0 = (tid & 3) << 4;
    const unsigned short* qh = qkvH + base + (size_t)(qt * 64 + r) * (3 * CD) + c0;
    const unsigned short* ql = qkvL + base + (size_t)(qt * 64 + r) * (3 * CD) + c0;
    *(uint4*)&Qh[r * FP + c0]     = *(const uint4*)qh;
    *(uint4*)&Qh[r * FP + c0 + 8] = *(const uint4*)(qh + 8);
    *(uint4*)&Ql[r * FP + c0]     = *(const uint4*)ql;
    *(uint4*)&Ql[r * FP + c0 + 8] = *(const uint4*)(ql + 8);
  }
  float m_i[4], l_i[4];
  f32x4 O[4];
  const f32x4 zero = {0.f, 0.f, 0.f, 0.f};
#pragma unroll
  for (int r = 0; r < 4; ++r) { m_i[r] = -INFINITY; l_i[r] = 0.f; }
#pragma unroll
  for (int d = 0; d < 4; ++d) O[d] = zero;

  // staging lane mappings
  const int skr = tid >> 2, skc = (tid & 3) << 4;        // K: 64 rows x 64 cols
  const int rp = (tid >> 3) << 1, c0v = (tid & 7) << 3;  // V: transposed pairs
  const unsigned short* kbH = qkvH + base + CD;
  const unsigned short* kbL = qkvL + base + CD;
  const unsigned short* vbH = qkvH + base + 2 * CD;
  const unsigned short* vbL = qkvL + base + 2 * CD;

  uint4 kh0, kh1, kl0, kl1, vxh, vyh, vxl, vyl;
  auto LOADJ = [&](int j) {
    const size_t ko = (size_t)(j * 64 + skr) * (3 * CD) + skc;
    kh0 = *(const uint4*)(kbH + ko);
    kh1 = *(const uint4*)(kbH + ko + 8);
    kl0 = *(const uint4*)(kbL + ko);
    kl1 = *(const uint4*)(kbL + ko + 8);
    const size_t vo = (size_t)(j * 64 + rp) * (3 * CD) + c0v;
    vxh = *(const uint4*)(vbH + vo);
    vyh = *(const uint4*)(vbH + vo + 3 * CD);
    vxl = *(const uint4*)(vbL + vo);
    vyl = *(const uint4*)(vbL + vo + 3 * CD);
  };

  LOADJ(0);
  for (int j = 0; j <= qt; ++j) {
    // write prefetched regs to LDS (implicit vmcnt wait on first use)
    *(uint4*)&Kh[skr * FP + skc]     = kh0;
    *(uint4*)&Kh[skr * FP + skc + 8] = kh1;
    *(uint4*)&Kl[skr * FP + skc]     = kl0;
    *(uint4*)&Kl[skr * FP + skc + 8] = kl1;
    {
      unsigned short xh[8], yh[8], xl[8], yl[8];
      *(uint4*)xh = vxh; *(uint4*)yh = vyh;
      *(uint4*)xl = vxl; *(uint4*)yl = vyl;
#pragma unroll
      for (int c = 0; c < 8; ++c) {
        const int R = c0v + c;
        const int col = rp ^ ((R >> 3) << 3);
        *(unsigned*)&Vth[R * FP + col] = (unsigned)xh[c] | ((unsigned)yh[c] << 16);
        *(unsigned*)&Vtl[R * FP + col] = (unsigned)xl[c] | ((unsigned)yl[c] << 16);
      }
    }
    __syncthreads();
    if (j < qt) LOADJ(j + 1);   // loads fly under QK^T + softmax + PV
    f32x4 S[4];
#pragma unroll
    for (int nt = 0; nt < 4; ++nt) S[nt] = zero;
#pragma unroll
    for (int kh2 = 0; kh2 < 2; ++kh2) {
      const short8 qh = *(const short8*)&Qh[(wave * 16 + r16) * FP + kh2 * 32 + quad * 8];
      const short8 ql = *(const short8*)&Ql[(wave * 16 + r16) * FP + kh2 * 32 + quad * 8];
#pragma unroll
      for (int nt = 0; nt < 4; ++nt) {
        const short8 kkh = *(const short8*)&Kh[(nt * 16 + r16) * FP + kh2 * 32 + quad * 8];
        const short8 kkl = *(const short8*)&Kl[(nt * 16 + r16) * FP + kh2 * 32 + quad * 8];
        S[nt] = __builtin_amdgcn_mfma_f32_16x16x32_bf16(qh, kkh, S[nt], 0, 0, 0);
        S[nt] = __builtin_amdgcn_mfma_f32_16x16x32_bf16(qh, kkl, S[nt], 0, 0, 0);
        S[nt] = __builtin_amdgcn_mfma_f32_16x16x32_bf16(ql, kkh, S[nt], 0, 0, 0);
      }
    }
#pragma unroll
    for (int r = 0; r < 4; ++r) {
      const int qrow = wave * 16 + quad * 4 + r;
      float s[4];
#pragma unroll
      for (int nt = 0; nt < 4; ++nt) {
        s[nt] = S[nt][r] * 0.125f;
        if (j == qt && (nt * 16 + r16) > qrow) s[nt] = -1e30f;
      }
      float rm = fmaxf(fmaxf(s[0], s[1]), fmaxf(s[2], s[3]));
#pragma unroll
      for (int o = 8; o > 0; o >>= 1) rm = fmaxf(rm, __shfl_xor(rm, o, 64));
      const float newm = fmaxf(m_i[r], rm);
      float p[4], rs = 0.f;
#pragma unroll
      for (int nt = 0; nt < 4; ++nt) { p[nt] = expf(s[nt] - newm); rs += p[nt]; }
#pragma unroll
      for (int o = 8; o > 0; o >>= 1) rs += __shfl_xor(rs, o, 64);
      const float alpha = expf(m_i[r] - newm);
      l_i[r] = l_i[r] * alpha + rs;
      m_i[r] = newm;
#pragma unroll
      for (int dt = 0; dt < 4; ++dt) O[dt][r] *= alpha;
#pragma unroll
      for (int nt = 0; nt < 4; ++nt)
        Pm[qrow * FP + nt * 16 + r16] = bf_hi(p[nt]);
    }
    __syncthreads();
#pragma unroll
    for (int kh2 = 0; kh2 < 2; ++kh2) {
      const short8 pa = *(const short8*)&Pm[(wave * 16 + r16) * FP + kh2 * 32 + quad * 8];
#pragma unroll
      for (int dt = 0; dt < 4; ++dt) {
        const int R = dt * 16 + r16;
        const int col = (kh2 * 32 + quad * 8) ^ ((R >> 3) << 3);
        const short8 vh = *(const short8*)&Vth[R * FP + col];
        const short8 vl = *(const short8*)&Vtl[R * FP + col];
        O[dt] = __builtin_amdgcn_mfma_f32_16x16x32_bf16(pa, vh, O[dt], 0, 0, 0);
        O[dt] = __builtin_amdgcn_mfma_f32_16x16x32_bf16(pa, vl, O[dt], 0, 0, 0);
      }
    }
    __syncthreads();   // LDS consumed; safe to overwrite next iteration
  }
#pragma unroll
  for (int r = 0; r < 4; ++r) {
    const float inv = 1.f / l_i[r];
    const size_t row = (size_t)b * CN + qt * 64 + wave * 16 + quad * 4 + r;
#pragma unroll
    for (int dt = 0; dt < 4; ++dt) {
      const size_t o = row * CD + head * CHD + dt * 16 + r16;
      split_store(O[dt][r] * inv, &outH[o], &outL[o]);
    }
  }
}

__global__ __launch_bounds__(256) void final_ln_p(const float* __restrict__ local,
                                                  const float* __restrict__ broad,
                                                  const float* __restrict__ g, const float* __restrict__ bb,
                                                  unsigned short* __restrict__ oh,
                                                  unsigned short* __restrict__ ol)
{
  const int r = blockIdx.x, t = threadIdx.x;
  __shared__ float red[4];
  const size_t lb = (size_t)r * CD;
  const size_t br = (size_t)(r >> 2) * CD;
  const float v0 = local[lb + t] + broad[br + t];
  const float v1 = local[lb + 256 + t] + broad[br + 256 + t];
  const float mu = blk_sum(v0 + v1, red) * (1.f / CD);
  const float d0 = v0 - mu, d1 = v1 - mu;
  const float var = blk_sum(d0 * d0 + d1 * d1, red) * (1.f / CD);
  const float inv = rsqrtf(var + CEPS);
  split_store(d0 * inv * g[t] + bb[t], &oh[lb + t], &ol[lb + t]);
  split_store(d1 * inv * g[t + 256] + bb[t + 256], &oh[lb + 256 + t], &ol[lb + 256 + t]);
}

// ---------------- launcher ----------------
extern "C" void kernel_launch(void* const* d_in, const int* in_sizes, int n_in,
                              void* d_out, int out_size, void* d_ws, size_t ws_size,
                              hipStream_t stream)
{
  (void)in_sizes; (void)n_in; (void)out_size; (void)ws_size;
  const int*   x         = (const int*)d_in[0];
  const float* emb       = (const float*)d_in[1];
  const float* pos_emb   = (const float*)d_in[2];
  const float* gru_w_ih  = (const float*)d_in[3];
  const float* gru_w_hh  = (const float*)d_in[4];
  const float* gru_b_ih  = (const float*)d_in[5];
  const float* gru_b_hh  = (const float*)d_in[6];
  const float* patch_g   = (const float*)d_in[7];
  const float* patch_b   = (const float*)d_in[8];
  const float* summ_w    = (const float*)d_in[9];
  const float* summ_b    = (const float*)d_in[10];
  const float* msg_w1    = (const float*)d_in[11];
  const float* msg_b1    = (const float*)d_in[12];
  const float* msg_w2    = (const float*)d_in[13];
  const float* msg_b2    = (const float*)d_in[14];
  const float* msg_ln_g  = (const float*)d_in[15];
  const float* msg_ln_b  = (const float*)d_in[16];
  const float* q_w       = (const float*)d_in[17];
  const float* q_b       = (const float*)d_in[18];
  const float* k_w       = (const float*)d_in[19];
  const float* k_b       = (const float*)d_in[20];
  const float* v_w       = (const float*)d_in[21];
  const float* v_b       = (const float*)d_in[22];
  const float* o_w       = (const float*)d_in[23];
  const float* o_b       = (const float*)d_in[24];
  const float* gc_w_ih   = (const float*)d_in[25];
  const float* gc_w_hh   = (const float*)d_in[26];
  const float* gc_b_ih   = (const float*)d_in[27];
  const float* gc_b_hh   = (const float*)d_in[28];
  const float* ar_ln_g   = (const float*)d_in[29];
  const float* ar_ln_b   = (const float*)d_in[30];
  const float* ar_qkv_w  = (const float*)d_in[31];
  const float* ar_qkv_b  = (const float*)d_in[32];
  const float* ar_out_w  = (const float*)d_in[33];
  const float* ar_out_b  = (const float*)d_in[34];
  const float* broad_w   = (const float*)d_in[35];
  const float* broad_b   = (const float*)d_in[36];
  const float* ln_g      = (const float*)d_in[37];
  const float* ln_b      = (const float*)d_in[38];
  const float* head_w    = (const float*)d_in[39];
  float* out = (float*)d_out;

  float* ws = (float*)d_ws;
  float* WL    = ws + OFF_LOCAL;
  float* X4    = ws + OFF_X4;
  float* GI    = X4;
  float* GHN   = X4 + (size_t)ROWS * 1536;
  float* WBR   = ws + OFF_MS;
  float* Wbias5 = ws + OFF_BIAS;
  unsigned short* WTh = (unsigned short*)(ws + OFF_WT);
  unsigned short* WTl = WTh + TOT_W;
  unsigned short* WhH = (unsigned short*)(ws + OFF_HP);
  unsigned short* WhL = WhH + PN;
  unsigned short* MsH = (unsigned short*)(ws + OFF_MS);
  unsigned short* MsL = MsH + PN;
  unsigned short* pAH = (unsigned short*)(ws + OFF_A);
  unsigned short* pAL = pAH + PN;
  unsigned short* pBH = (unsigned short*)(ws + OFF_B);
  unsigned short* pBL = pBH + PN;
  unsigned short* QkH = (unsigned short*)X4;
  unsigned short* QkL = QkH + (size_t)ROWS * 1536;
  unsigned short* FnH = (unsigned short*)X4;
  unsigned short* FnL = FnH + (size_t)TROWS * CD;

  const int EW = ROWS * CD / 256;
  const float inv_sqrt_d = 0.04419417382415922f;

  auto TR = [&](const float* in, size_t off, int K, int N, int ldk, int ko) {
    transpose_split<<<dim3(N / 32, K / 32), 256, 0, stream>>>(in, WTh + off, WTl + off, K, N, ldk, ko);
  };
  TR(gru_w_ih, T_GRU_IH, 512, 1536, 512, 0);
  TR(gru_w_hh, T_GRU_HH, 512, 1536, 512, 0);
  TR(summ_w,   T_SUMM,   512, 512,  512, 0);
  TR(msg_w1,                      T_FUSE,           512, 512, 512, 0);
  TR(msg_w1 + (size_t)512 * 512,  T_FUSE + 262144,  512, 512, 512, 0);
  TR(q_w,                         T_FUSE + 524288,  512, 512, 512, 0);
  TR(k_w,                         T_FUSE + 786432,  512, 512, 512, 0);
  TR(v_w,                         T_FUSE + 1048576, 512, 512, 512, 0);
  TR(msg_w2,   T_MSG2,   512, 512,  512, 0);
  TR(o_w, T_OW, 512, 512, 512, 0);
  TR(gc_w_ih,                       T_GCAB, 512, 1536, 1024, 0);
  TR(gc_w_ih + (size_t)512 * 1536,  T_GCAB, 512, 1536, 1024, 512);
  TR(gc_w_hh,  T_GC_HH,  512, 1536, 512, 0);
  TR(ar_qkv_w, T_AR_QKV, 512, 1536, 512, 0);
  TR(ar_out_w, T_AR_OUT, 512, 512,  512, 0);
  TR(broad_w,  T_BROAD,  512, 512,  512, 0);
  TR(head_w,   T_HEAD,   512, 256,  512, 0);
  concat_bias5<<<10, 256, 0, stream>>>(msg_b1, q_b, k_b, v_b, Wbias5);

  // big weight GEMM (2-product)
  auto G3 = [&](const unsigned short* AH_, const unsigned short* AL_, int lda_,
                size_t toff, int ldb_, const float* bias_, float* Cf_, int ldc_, float* Cf2_,
                unsigned short* CHp_, unsigned short* CLp_, int ldcp_,
                int K_, int flags_, int gx, int gy) {
    gemm_bf3<false><<<dim3(gx, gy), 256, 0, stream>>>(
        AH_, AL_, AH_, AL_, K_, lda_, WTh + toff, WTl + toff, ldb_, bias_, 1.f,
        Cf_, ldc_, Cf2_, CHp_, CLp_, ldcp_, K_, flags_, 0, 0, 0);
  };
  // small weight GEMM (64x128, 2-product)
  auto G3S = [&](const unsigned short* AH_, const unsigned short* AL_, int lda_,
                 size_t toff, const float* bias_, float* Cf_, int ldc_,
                 unsigned short* CHp_, unsigned short* CLp_, int ldcp_,
                 int flags_, int gx, int gy) {
    gemm_bf3s<<<dim3(gx, gy), 256, 0, stream>>>(
        AH_, AL_, lda_, WTh + toff, 512, bias_,
        Cf_, ldc_, CHp_, CLp_, ldcp_, 512, flags_);
  };

  // ---- patch GRU over P=4 steps ----
  zero_k<<<EW, 256, 0, stream>>>(ws + OFF_HP);
  for (int t = 0; t < CP; ++t) {
    embed_p<<<EW, 256, 0, stream>>>(x, emb, pos_emb, pAH, pAL, t);
    G3(pAH, pAL, 512, T_GRU_IH, 512, gru_b_ih, GI, 1536, nullptr,
       nullptr, nullptr, 0, 512, F_WR_F32, 12, 64);
    G3(WhH, WhL, 512, T_GRU_HH, 512, gru_b_hh, GI, 1536, GHN,
       nullptr, nullptr, 0, 512, F_SPLIT, 12, 64);
    gru_point_p<<<EW, 256, 0, stream>>>(GI, GHN, WhH, WhL, WL, t);
  }
  ln_rows<<<TROWS, 256, 0, stream>>>(WL, WL, patch_g, patch_b);
  mean_pool_p<<<EW, 256, 0, stream>>>(WL, pAH, pAL);
  G3S(pAH, pAL, 512, T_SUMM, summ_b, nullptr, 0, WhH, WhL, 512, F_WR_PAIR, 4, 128);

  // ---- rounds ----
  for (int rnd = 0; rnd < 6; ++rnd) {
    G3(WhH, WhL, 512, T_FUSE, 512, Wbias5, X4, 2560, nullptr,
       nullptr, nullptr, 0, 512, F_WR_F32, 20, 64);
    msg_gelu_p<<<EW, 256, 0, stream>>>(X4, pBH, pBL);
    G3S(pBH, pBL, 512, T_MSG2, msg_b2, nullptr, 0, MsH, MsL, 512, F_WR_PAIR, 4, 128);
    rotary2_p<<<ROWS, 256, 0, stream>>>(X4, pAH, pAL, pBH, pBL);
    // scores (3-product, lower-triangular 128-tiles) -> X4 cols 0..1023
    gemm_bf3<true><<<dim3(36, 1, CB), 256, 0, stream>>>(
        pAH, pAL, pAH, pAL, 512, 512, pBH, pBL, 512, nullptr, inv_sqrt_d,
        X4, 2560, nullptr, nullptr, nullptr, 0, 512, F_WR_F32 | F_TRI,
        (long long)CN * CD, (long long)CN * CD, (long long)CN * 2560);
    topk_attn<<<ROWS / 4, 256, 0, stream>>>(X4, pAH, pAL);
    G3S(pAH, pAL, 512, T_OW, o_b, nullptr, 0, pBH, pBL, 512, F_WR_PAIR, 4, 128);
    gemm_bf3<false><<<dim3(12, 64), 256, 0, stream>>>(
        MsH, MsL, pBH, pBL, 512, 512, WTh + T_GCAB, WTl + T_GCAB, 1024, gc_b_ih, 1.f,
        GI, 1536, nullptr, nullptr, nullptr, 0, 1024, F_WR_F32, 0, 0, 0);
    G3(WhH, WhL, 512, T_GC_HH, 512, gc_b_hh, GI, 1536, GHN,
       nullptr, nullptr, 0, 512, F_SPLIT, 12, 64);
    if ((rnd & 1) == 1) {
      gru_ln_p<<<ROWS, 256, 0, stream>>>(GI, GHN, WhH, WhL, msg_ln_g, msg_ln_b,
                                         pAH, pAL, ar_ln_g, ar_ln_b);
      G3(pAH, pAL, 512, T_AR_QKV, 512, ar_qkv_b, nullptr, 0, nullptr,
         QkH, QkL, 1536, 512, F_WR_PAIR, 12, 64);
      flash_attn_p<<<dim3(16 * CH * CB), 256, 0, stream>>>(QkH, QkL, pBH, pBL);
      G3S(pBH, pBL, 512, T_AR_OUT, ar_out_b, nullptr, 0, WhH, WhL, 512,
          F_ACC_PAIR | F_WR_PAIR, 4, 128);
    } else {
      gru_ln_p<<<ROWS, 256, 0, stream>>>(GI, GHN, WhH, WhL, msg_ln_g, msg_ln_b,
                                         nullptr, nullptr, nullptr, nullptr);
    }
  }

  // ---- head ----
  G3S(WhH, WhL, 512, T_BROAD, broad_b, WBR, 512, nullptr, nullptr, 0, F_WR_F32, 4, 128);
  final_ln_p<<<TROWS, 256, 0, stream>>>(WL, WBR, ln_g, ln_b, FnH, FnL);
  G3S(FnH, FnL, 512, T_HEAD, nullptr, out, CV, nullptr, nullptr, 0, F_WR_F32, 2, 512);
}

// Round 7
// 3593.064 us; speedup vs baseline: 1.0317x; 1.0317x over previous
//
#include <hip/hip_runtime.h>
#include <math.h>

// ---------------- problem constants ----------------
constexpr int CB = 8, CT = 4096, CP = 4, CD = 512, CV = 256;
constexpr int CN = 1024, CK = 16, CH = 8, CHD = 64;
constexpr int ROWS = CB * CN;     // 8192
constexpr int TROWS = CB * CT;    // 32768
constexpr float CEPS = 1e-5f;
constexpr size_t PN = (size_t)ROWS * CD;   // 4,194,304 (one pair-plane)

// ---------------- workspace layout (floats) ----------------
constexpr size_t OFF_LOCAL = 0;                                    // 16,777,216 fp32 local
constexpr size_t OFF_HP    = OFF_LOCAL + (size_t)ROWS * CP * CD;   //  4,194,304 h pair
constexpr size_t OFF_X4    = OFF_HP    + PN;                       // 20,971,520 fused5/scores/gi+ghn/arqkv/final
constexpr size_t OFF_MS    = OFF_X4    + (size_t)ROWS * 2560;      //  4,194,304 msgs pair / broad fp32
constexpr size_t OFF_A     = OFF_MS    + PN;                       //  4,194,304 pair A
constexpr size_t OFF_B     = OFF_A     + PN;                       //  4,194,304 pair B
constexpr size_t OFF_BIAS  = OFF_B     + PN;                       //      4,096
constexpr size_t OFF_WT    = OFF_BIAS  + 4096;                     //  7,471,104
// end = 62,011,008 floats = 236.6 MiB

constexpr size_t TOT_W    = 7471104;
constexpr size_t T_GRU_IH = 0;                     // 1536x512
constexpr size_t T_GRU_HH = 786432;                // 1536x512
constexpr size_t T_SUMM   = 1572864;               // 512x512
constexpr size_t T_FUSE   = 1835008;               // 2560x512 (msg1a|msg1b|qw|kw|vw)
constexpr size_t T_MSG2   = 3145728;               // 512x512
constexpr size_t T_OW     = 3407872;               // 512x512
constexpr size_t T_GCAB   = 3670016;               // 1536x1024 ([gc_top|gc_bot] along K)
constexpr size_t T_GC_HH  = 5242880;               // 1536x512
constexpr size_t T_AR_QKV = 6029312;               // 1536x512
constexpr size_t T_AR_OUT = 6815744;               // 512x512
constexpr size_t T_BROAD  = 7077888;               // 512x512
constexpr size_t T_HEAD   = 7340032;               // 256x512

// GEMM flags
constexpr int F_ACC_F32  = 1;
constexpr int F_ACC_PAIR = 2;
constexpr int F_WR_F32   = 4;
constexpr int F_WR_PAIR  = 8;
constexpr int F_TRI      = 16;
constexpr int F_SPLIT    = 32;   // col<1024: accumulate into Cf; col>=1024: write Cf2

// ---------------- device helpers ----------------
typedef __attribute__((ext_vector_type(8))) short short8;
typedef __attribute__((ext_vector_type(4))) float f32x4;
typedef __attribute__((ext_vector_type(16))) float f32x16;

__device__ __forceinline__ float sigm(float x) { return 1.f / (1.f + expf(-x)); }
__device__ __forceinline__ float geluf(float x) {
  return 0.5f * x * (1.f + erff(x * 0.7071067811865475f));
}
__device__ __forceinline__ unsigned short bf_hi(float x) {
  const unsigned u = __float_as_uint(x);
  return (unsigned short)((u + 0x7FFFu + ((u >> 16) & 1u)) >> 16);
}
__device__ __forceinline__ float bf_f(unsigned short h) {
  return __uint_as_float((unsigned)h << 16);
}
__device__ __forceinline__ void split_store(float v, unsigned short* ph, unsigned short* pl) {
  const unsigned short h = bf_hi(v);
  *ph = h; *pl = bf_hi(v - bf_f(h));
}
__device__ __forceinline__ float blk_sum(float v, float* red) {
#pragma unroll
  for (int o = 32; o > 0; o >>= 1) v += __shfl_down(v, o, 64);
  const int wv = threadIdx.x >> 6, ln = threadIdx.x & 63;
  __syncthreads();
  if (ln == 0) red[wv] = v;
  __syncthreads();
  return red[0] + red[1] + red[2] + red[3];
}

// bijective XCD swizzle (m204): dispatcher assigns consecutive flat block ids
// round-robin across 8 XCDs; remap so each XCD owns a CONTIGUOUS chunk of the
// work-id space -> neighboring tiles (sharing A/B panels / K-V groups / batch
// slices) hit the same L2.
__device__ __forceinline__ int xcd_swz(int i, int n) {
  if (n < 8) return i;
  const int q = n >> 3, r = n & 7;
  const int xcd = i & 7, slot = i >> 3;
  return (xcd < r ? xcd * (q + 1) : r * (q + 1) + (xcd - r) * q) + slot;
}

// ---------------- transpose + bf16 split (weights) ----------------
__global__ __launch_bounds__(256) void transpose_split(const float* __restrict__ in,
                                                       unsigned short* __restrict__ oh,
                                                       unsigned short* __restrict__ ol,
                                                       int K, int N, int ldk, int ko)
{
  __shared__ float tile[32][33];
  const int n0 = blockIdx.x * 32, k0 = blockIdx.y * 32;
  const int tx = threadIdx.x & 31, ty = threadIdx.x >> 5;
#pragma unroll
  for (int i = 0; i < 32; i += 8)
    tile[ty + i][tx] = in[(size_t)(k0 + ty + i) * N + n0 + tx];
  __syncthreads();
#pragma unroll
  for (int i = 0; i < 32; i += 8) {
    const float v = tile[tx][ty + i];
    const unsigned short h = bf_hi(v);
    const size_t o = (size_t)(n0 + ty + i) * ldk + ko + k0 + tx;
    oh[o] = h;
    ol[o] = bf_hi(v - bf_f(h));
  }
}

__global__ void concat_bias5(const float* __restrict__ b1, const float* __restrict__ qb,
                             const float* __restrict__ kb, const float* __restrict__ vb,
                             float* __restrict__ o)
{
  const int i = blockIdx.x * 256 + threadIdx.x;   // 2560
  float v;
  if (i < 512) v = b1[i];
  else if (i < 1024) v = 0.f;
  else if (i < 1536) v = qb[i - 1024];
  else if (i < 2048) v = kb[i - 1536];
  else v = vb[i - 2048];
  o[i] = v;
}

// ---------------- bf16 MFMA GEMM (128x128 tile, 32x32x16 MFMA) ----------
// Wave tile 64x64 = 2x2 sub-tiles of 32x32. Correctness of the fragment
// layouts proven in round 6 (absmax identical). This round reorders the
// inner loop so each accumulator is re-touched only every 4 MFMAs —
// in-order issue no longer stalls on the 32x32 dep-latency.
// A/B frag: row/col = lane&31, k = (lane>>5)*8 + e (8 contiguous).
// C/D frag (HW-verified m74/m101): col = lane&31,
//   row = (reg&3) + 8*(reg>>2) + 4*(lane>>5).
// P3=true : 3-product (ah*bh + ah*bl + al*bh) — fp32-grade both sides (scores).
// P3=false: 2-product (ah*bh + al*bh) — A fp32-grade, B truncated to bf16.
template <bool P3>
__global__ __launch_bounds__(256, 2) void gemm_bf3(
    const unsigned short* __restrict__ AH, const unsigned short* __restrict__ AL,
    const unsigned short* __restrict__ A2H, const unsigned short* __restrict__ A2L,
    int K1, int lda,
    const unsigned short* __restrict__ BH, const unsigned short* __restrict__ BL, int ldb,
    const float* __restrict__ bias, float scale,
    float* __restrict__ Cf, int ldc, float* __restrict__ Cf2,
    unsigned short* __restrict__ CHp, unsigned short* __restrict__ CLp, int ldcp,
    int K, int flags, long long sA, long long sB, long long sC)
{
  AH += (size_t)blockIdx.z * sA; AL += (size_t)blockIdx.z * sA;
  BH += (size_t)blockIdx.z * sB; BL += (size_t)blockIdx.z * sB;
  if (Cf) Cf += (size_t)blockIdx.z * sC;
  int bm, bn;
  if (flags & F_TRI) {
    int t = xcd_swz(blockIdx.x, gridDim.x), i = 0, acc0 = 0;
    while (acc0 + i + 1 <= t) { ++i; acc0 += i; }
    bm = i << 7; bn = (t - acc0) << 7;
  } else {
    const int w = xcd_swz(blockIdx.x + gridDim.x * blockIdx.y, gridDim.x * gridDim.y);
    bm = (w / gridDim.x) << 7; bn = (w % gridDim.x) << 7;
  }
  __shared__ __align__(16) unsigned short AsH[128][40];
  __shared__ __align__(16) unsigned short AsL[128][40];
  __shared__ __align__(16) unsigned short BsH[128][40];
  __shared__ __align__(16) unsigned short BsL[P3 ? 128 : 1][40];
  const int tid = threadIdx.x;
  const int lane = tid & 63, wave = tid >> 6;
  const int wm = (wave & 1) << 6, wn = (wave >> 1) << 6;
  const int l31 = lane & 31, half = lane >> 5;
  const int sr = tid >> 1, sc = (tid & 1) << 4;
  f32x16 acc[2][2];
#pragma unroll
  for (int i = 0; i < 2; ++i)
#pragma unroll
    for (int j = 0; j < 2; ++j)
#pragma unroll
      for (int e = 0; e < 16; ++e) acc[i][j][e] = 0.f;

  for (int k0 = 0; k0 < K; k0 += 32) {
    const int kc = k0 + sc;
    const unsigned short *pAH, *pAL;
    if (kc < K1) {
      pAH = AH + (size_t)(bm + sr) * lda + kc;
      pAL = AL + (size_t)(bm + sr) * lda + kc;
    } else {
      pAH = A2H + (size_t)(bm + sr) * lda + (kc - K1);
      pAL = A2L + (size_t)(bm + sr) * lda + (kc - K1);
    }
    const unsigned short* pBH = BH + (size_t)(bn + sr) * ldb + kc;
    *(uint4*)&AsH[sr][sc]     = *(const uint4*)pAH;
    *(uint4*)&AsH[sr][sc + 8] = *(const uint4*)(pAH + 8);
    *(uint4*)&AsL[sr][sc]     = *(const uint4*)pAL;
    *(uint4*)&AsL[sr][sc + 8] = *(const uint4*)(pAL + 8);
    *(uint4*)&BsH[sr][sc]     = *(const uint4*)pBH;
    *(uint4*)&BsH[sr][sc + 8] = *(const uint4*)(pBH + 8);
    if (P3) {
      const unsigned short* pBL = BL + (size_t)(bn + sr) * ldb + kc;
      *(uint4*)&BsL[sr][sc]     = *(const uint4*)pBL;
      *(uint4*)&BsL[sr][sc + 8] = *(const uint4*)(pBL + 8);
    }
    __syncthreads();
    // ks-major, product-pass-major order: each acc re-touched every 4 MFMAs.
#pragma unroll
    for (int ks = 0; ks < 2; ++ks) {
      const int ko = ks * 16 + half * 8;
      const short8 a0h = *(const short8*)&AsH[wm + l31][ko];
      const short8 a1h = *(const short8*)&AsH[wm + 32 + l31][ko];
      const short8 a0l = *(const short8*)&AsL[wm + l31][ko];
      const short8 a1l = *(const short8*)&AsL[wm + 32 + l31][ko];
      const short8 b0h = *(const short8*)&BsH[wn + l31][ko];
      const short8 b1h = *(const short8*)&BsH[wn + 32 + l31][ko];
      acc[0][0] = __builtin_amdgcn_mfma_f32_32x32x16_bf16(a0h, b0h, acc[0][0], 0, 0, 0);
      acc[0][1] = __builtin_amdgcn_mfma_f32_32x32x16_bf16(a0h, b1h, acc[0][1], 0, 0, 0);
      acc[1][0] = __builtin_amdgcn_mfma_f32_32x32x16_bf16(a1h, b0h, acc[1][0], 0, 0, 0);
      acc[1][1] = __builtin_amdgcn_mfma_f32_32x32x16_bf16(a1h, b1h, acc[1][1], 0, 0, 0);
      acc[0][0] = __builtin_amdgcn_mfma_f32_32x32x16_bf16(a0l, b0h, acc[0][0], 0, 0, 0);
      acc[0][1] = __builtin_amdgcn_mfma_f32_32x32x16_bf16(a0l, b1h, acc[0][1], 0, 0, 0);
      acc[1][0] = __builtin_amdgcn_mfma_f32_32x32x16_bf16(a1l, b0h, acc[1][0], 0, 0, 0);
      acc[1][1] = __builtin_amdgcn_mfma_f32_32x32x16_bf16(a1l, b1h, acc[1][1], 0, 0, 0);
      if (P3) {
        const short8 b0l = *(const short8*)&BsL[wn + l31][ko];
        const short8 b1l = *(const short8*)&BsL[wn + 32 + l31][ko];
        acc[0][0] = __builtin_amdgcn_mfma_f32_32x32x16_bf16(a0h, b0l, acc[0][0], 0, 0, 0);
        acc[0][1] = __builtin_amdgcn_mfma_f32_32x32x16_bf16(a0h, b1l, acc[0][1], 0, 0, 0);
        acc[1][0] = __builtin_amdgcn_mfma_f32_32x32x16_bf16(a1h, b0l, acc[1][0], 0, 0, 0);
        acc[1][1] = __builtin_amdgcn_mfma_f32_32x32x16_bf16(a1h, b1l, acc[1][1], 0, 0, 0);
      }
    }
    __syncthreads();
  }
#pragma unroll
  for (int mi = 0; mi < 2; ++mi) {
#pragma unroll
    for (int ni = 0; ni < 2; ++ni) {
      const int col = bn + wn + ni * 32 + l31;
      const float bv = bias ? bias[col] : 0.f;
#pragma unroll
      for (int reg = 0; reg < 16; ++reg) {
        const int row = bm + wm + mi * 32 + (reg & 3) + ((reg >> 2) << 3) + (half << 2);
        float o = acc[mi][ni][reg] * scale + bv;
        if (flags & F_SPLIT) {
          if (col < 1024) {
            float* p = Cf + (size_t)row * ldc + col;
            *p = o + *p;
          } else {
            Cf2[(size_t)row * 512 + (col - 1024)] = o;
          }
        } else {
          if (flags & F_ACC_F32) o += Cf[(size_t)row * ldc + col];
          if (flags & F_ACC_PAIR) {
            const size_t ip = (size_t)row * ldcp + col;
            o += bf_f(CHp[ip]) + bf_f(CLp[ip]);
          }
          if (flags & F_WR_F32) Cf[(size_t)row * ldc + col] = o;
          if (flags & F_WR_PAIR) {
            const size_t ip = (size_t)row * ldcp + col;
            split_store(o, &CHp[ip], &CLp[ip]);
          }
        }
      }
    }
  }
}

// ---------------- small-tile variant: 64x128, 2-product ----------
__global__ __launch_bounds__(256, 3) void gemm_bf3s(
    const unsigned short* __restrict__ AH, const unsigned short* __restrict__ AL, int lda,
    const unsigned short* __restrict__ BH, int ldb,
    const float* __restrict__ bias,
    float* __restrict__ Cf, int ldc,
    unsigned short* __restrict__ CHp, unsigned short* __restrict__ CLp, int ldcp,
    int K, int flags)
{
  const int w = xcd_swz(blockIdx.x + gridDim.x * blockIdx.y, gridDim.x * gridDim.y);
  const int bm = (w / gridDim.x) << 6, bn = (w % gridDim.x) << 7;
  __shared__ __align__(16) unsigned short AsH[64][40];
  __shared__ __align__(16) unsigned short AsL[64][40];
  __shared__ __align__(16) unsigned short BsH[128][40];
  const int tid = threadIdx.x;
  const int lane = tid & 63, wave = tid >> 6;
  const int wm = (wave & 1) << 5, wn = (wave >> 1) << 6;
  const int r16 = lane & 15, quad = lane >> 4;
  const int sar = tid >> 2, sac = (tid & 3) << 3;
  const int sbr = tid >> 1, sbc = (tid & 1) << 4;
  const f32x4 zero = {0.f, 0.f, 0.f, 0.f};
  f32x4 acc[2][4];
#pragma unroll
  for (int i = 0; i < 2; ++i)
#pragma unroll
    for (int j = 0; j < 4; ++j) acc[i][j] = zero;

  for (int k0 = 0; k0 < K; k0 += 32) {
    const unsigned short* pAH = AH + (size_t)(bm + sar) * lda + k0 + sac;
    const unsigned short* pAL = AL + (size_t)(bm + sar) * lda + k0 + sac;
    const unsigned short* pBH = BH + (size_t)(bn + sbr) * ldb + k0 + sbc;
    *(uint4*)&AsH[sar][sac] = *(const uint4*)pAH;
    *(uint4*)&AsL[sar][sac] = *(const uint4*)pAL;
    *(uint4*)&BsH[sbr][sbc]     = *(const uint4*)pBH;
    *(uint4*)&BsH[sbr][sbc + 8] = *(const uint4*)(pBH + 8);
    __syncthreads();
    short8 bh[4];
#pragma unroll
    for (int ni = 0; ni < 4; ++ni)
      bh[ni] = *(const short8*)&BsH[wn + ni * 16 + r16][quad * 8];
#pragma unroll
    for (int mi = 0; mi < 2; ++mi) {
      const short8 ah = *(const short8*)&AsH[wm + mi * 16 + r16][quad * 8];
      const short8 al = *(const short8*)&AsL[wm + mi * 16 + r16][quad * 8];
#pragma unroll
      for (int ni = 0; ni < 4; ++ni) {
        acc[mi][ni] = __builtin_amdgcn_mfma_f32_16x16x32_bf16(ah, bh[ni], acc[mi][ni], 0, 0, 0);
        acc[mi][ni] = __builtin_amdgcn_mfma_f32_16x16x32_bf16(al, bh[ni], acc[mi][ni], 0, 0, 0);
      }
    }
    __syncthreads();
  }
#pragma unroll
  for (int mi = 0; mi < 2; ++mi) {
    const int row0 = bm + wm + mi * 16 + quad * 4;
#pragma unroll
    for (int ni = 0; ni < 4; ++ni) {
      const int col = bn + wn + ni * 16 + r16;
      const float bv = bias ? bias[col] : 0.f;
#pragma unroll
      for (int rg = 0; rg < 4; ++rg) {
        const int row = row0 + rg;
        float o = acc[mi][ni][rg] + bv;
        if (flags & F_ACC_PAIR) {
          const size_t ip = (size_t)row * ldcp + col;
          o += bf_f(CHp[ip]) + bf_f(CLp[ip]);
        }
        if (flags & F_WR_F32) Cf[(size_t)row * ldc + col] = o;
        if (flags & F_WR_PAIR) {
          const size_t ip = (size_t)row * ldcp + col;
          split_store(o, &CHp[ip], &CLp[ip]);
        }
      }
    }
  }
}

// ---------------- small kernels ----------------
__global__ void zero_k(float* __restrict__ p) {
  p[(size_t)blockIdx.x * 256 + threadIdx.x] = 0.f;
}

__global__ void embed_p(const int* __restrict__ x, const float* __restrict__ emb,
                        const float* __restrict__ pos,
                        unsigned short* __restrict__ oh, unsigned short* __restrict__ ol, int t)
{
  const int i = blockIdx.x * 256 + threadIdx.x;
  const int r = i >> 9, d = i & 511;
  const int b = r >> 10, n = r & (CN - 1);
  const int tok = x[b * CT + n * CP + t];
  const float v = emb[(size_t)tok * CD + d] + pos[t * CD + d];
  split_store(v, &oh[i], &ol[i]);
}

__global__ void gru_point_p(const float* __restrict__ gi, const float* __restrict__ ghn,
                            unsigned short* __restrict__ hH, unsigned short* __restrict__ hL,
                            float* __restrict__ hs, int t)
{
  const int i = blockIdx.x * 256 + threadIdx.x;
  const int r = i >> 9, d = i & 511;
  const size_t gb = (size_t)r * (3 * CD) + d;
  const float sr_ = gi[gb], sz = gi[gb + CD], inn = gi[gb + 2 * CD];
  const float hn = ghn[i];
  const float hp = bf_f(hH[i]) + bf_f(hL[i]);
  const float rr = sigm(sr_), zz = sigm(sz);
  const float nn = tanhf(inn + rr * hn);
  const float hv = (1.f - zz) * nn + zz * hp;
  split_store(hv, &hH[i], &hL[i]);
  hs[(size_t)r * (CP * CD) + (size_t)t * CD + d] = hv;
}

__global__ __launch_bounds__(256) void ln_rows(const float* __restrict__ in, float* __restrict__ out,
                                               const float* __restrict__ g, const float* __restrict__ b)
{
  const int r = blockIdx.x, t = threadIdx.x;
  __shared__ float red[4];
  const float* ip = in + (size_t)r * CD;
  const float v0 = ip[t], v1 = ip[t + 256];
  const float mu = blk_sum(v0 + v1, red) * (1.f / CD);
  const float d0 = v0 - mu, d1 = v1 - mu;
  const float var = blk_sum(d0 * d0 + d1 * d1, red) * (1.f / CD);
  const float inv = rsqrtf(var + CEPS);
  float* op = out + (size_t)r * CD;
  op[t] = d0 * inv * g[t] + b[t];
  op[t + 256] = d1 * inv * g[t + 256] + b[t + 256];
}

__global__ void mean_pool_p(const float* __restrict__ local,
                            unsigned short* __restrict__ oh, unsigned short* __restrict__ ol)
{
  const int i = blockIdx.x * 256 + threadIdx.x;
  const int r = i >> 9, d = i & 511;
  const float* p = local + (size_t)r * (CP * CD) + d;
  split_store(0.25f * (p[0] + p[CD] + p[2 * CD] + p[3 * CD]), &oh[i], &ol[i]);
}

__global__ void msg_gelu_p(const float* __restrict__ X4,
                           unsigned short* __restrict__ oh, unsigned short* __restrict__ ol)
{
  const int i = blockIdx.x * 256 + threadIdx.x;
  const int r = i >> 9, d = i & 511;
  const int n = r & (CN - 1);
  const float pv = X4[(size_t)r * 2560 + d];
  float acc = 0.f;
#pragma unroll
  for (int w = 0; w <= 4; ++w) {
    const float xv = pv + ((n >= w) ? X4[(size_t)(r - w) * 2560 + 512 + d] : 0.f);
    acc += geluf(xv);
  }
  split_store(acc * 0.2f, &oh[i], &ol[i]);
}

__global__ void rotary2_p(const float* __restrict__ X4,
                          unsigned short* __restrict__ qh, unsigned short* __restrict__ ql,
                          unsigned short* __restrict__ kh, unsigned short* __restrict__ kl)
{
  const int i = blockIdx.x * 256 + threadIdx.x;   // ROWS*256
  const int r = i >> 8, j = i & 255;
  const int n = r & (CN - 1);
  const float fr = (float)n * expf(-9.210340371976184f * ((float)j * (1.f / 256.f)));
  float s, c;
  sincosf(fr, &s, &c);
  const float* p = X4 + (size_t)r * 2560;
  const size_t o0 = (size_t)r * CD + j, o1 = o0 + 256;
  const float q1 = p[1024 + j], q2 = p[1024 + 256 + j];
  split_store(q1 * c - q2 * s, &qh[o0], &ql[o0]);
  split_store(q2 * c + q1 * s, &qh[o1], &ql[o1]);
  const float k1 = p[1536 + j], k2 = p[1536 + 256 + j];
  split_store(k1 * c - k2 * s, &kh[o0], &kl[o0]);
  split_store(k2 * c + k1 * s, &kh[o1], &kl[o1]);
}

// ---------------- fused top-K + softmax + gather ----------------
// One WAVE per row (4 rows per block): single-phase selection -> serial
// reduce-chain halves vs the 2-phase block version; no __syncthreads at all.
// Batch-per-XCD swizzle keeps each batch's 2 MB V-slice L2-resident.
__global__ __launch_bounds__(256) void topk_attn(const float* __restrict__ X4,
                                                 unsigned short* __restrict__ ctxH,
                                                 unsigned short* __restrict__ ctxL)
{
  const int g = xcd_swz(blockIdx.x, gridDim.x);
  const int wave = threadIdx.x >> 6, lane = threadIdx.x & 63;
  const int r = g * 4 + wave;
  const int b = r >> 10, n = r & (CN - 1);
  const float* row = X4 + (size_t)r * 2560;
  __shared__ float p16s[4][CK];
  __shared__ int   i16s[4][CK];

  unsigned long long key[16];
#pragma unroll
  for (int q = 0; q < 16; ++q) {
    const int m = q * 64 + lane;
    const float v = (m <= n) ? row[m] : -INFINITY;
    unsigned u = __float_as_uint(v);
    u = (u & 0x80000000u) ? ~u : (u | 0x80000000u);
    key[q] = ((unsigned long long)u << 32) | (unsigned)(CN - 1 - m);
  }
  // per-lane max via tree (ILP-friendly)
  unsigned long long lane_best;
  {
    unsigned long long t[8];
#pragma unroll
    for (int i = 0; i < 8; ++i) t[i] = key[i] > key[i + 8] ? key[i] : key[i + 8];
#pragma unroll
    for (int i = 0; i < 4; ++i) t[i] = t[i] > t[i + 4] ? t[i] : t[i + 4];
    t[0] = t[0] > t[2] ? t[0] : t[2];
    t[1] = t[1] > t[3] ? t[1] : t[3];
    lane_best = t[0] > t[1] ? t[0] : t[1];
  }
  unsigned long long mine = 0ull;
#pragma unroll
  for (int it = 0; it < CK; ++it) {
    unsigned long long best = lane_best;
#pragma unroll
    for (int o = 32; o > 0; o >>= 1) {
      const unsigned long long o2 = __shfl_xor(best, o, 64);
      best = best > o2 ? best : o2;
    }
    if (lane == it) mine = best;
    if (lane_best == best) {   // exactly one lane (keys unique via index bits)
#pragma unroll
      for (int q = 0; q < 16; ++q)
        if (key[q] == best) key[q] = 0ull;
      unsigned long long t[8];
#pragma unroll
      for (int i = 0; i < 8; ++i) t[i] = key[i] > key[i + 8] ? key[i] : key[i + 8];
#pragma unroll
      for (int i = 0; i < 4; ++i) t[i] = t[i] > t[i + 4] ? t[i] : t[i + 4];
      t[0] = t[0] > t[2] ? t[0] : t[2];
      t[1] = t[1] > t[3] ? t[1] : t[3];
      lane_best = t[0] > t[1] ? t[0] : t[1];
    }
  }
  // lanes 0..15 hold the sorted top-16; softmax among them (wave-local)
  unsigned u = (unsigned)(mine >> 32);
  u = (u & 0x80000000u) ? (u & 0x7FFFFFFFu) : ~u;
  const float val = __uint_as_float(u);
  const int idx = CN - 1 - (int)(mine & 0xFFFFFFFFu);
  const float mx = __shfl(val, 0, 64);   // it=0 winner is the global max
  float e = 0.f;
  if (lane < CK && val != -INFINITY) e = expf(val - mx);
  float sum = e;
#pragma unroll
  for (int o = 8; o > 0; o >>= 1) sum += __shfl_xor(sum, o, 64);
  if (lane < CK) {
    p16s[wave][lane] = e / sum;
    i16s[wave][lane] = idx;
  }
  // wave-local LDS RAW: wave executes in lockstep, DS ops in order — no barrier
  float pr[CK];
  int   ro[CK];
  const int vb = b << 10;
#pragma unroll
  for (int q = 0; q < CK; ++q) {
    pr[q] = p16s[wave][q];
    ro[q] = (vb + i16s[wave][q]) * 2560 + 2048;
  }
#pragma unroll
  for (int pass = 0; pass < 8; ++pass) {
    const int d = pass * 64 + lane;
    float a = 0.f;
#pragma unroll
    for (int q = 0; q < CK; ++q)
      a += pr[q] * X4[(size_t)ro[q] + d];
    split_store(a, &ctxH[(size_t)r * CD + d], &ctxL[(size_t)r * CD + d]);
  }
}

// gru + msg-LN; optionally also ar-LN of the new h -> (aH,aL)
__global__ __launch_bounds__(256) void gru_ln_p(const float* __restrict__ gi, const float* __restrict__ ghn,
                                                unsigned short* __restrict__ hH, unsigned short* __restrict__ hL,
                                                const float* __restrict__ g, const float* __restrict__ b,
                                                unsigned short* __restrict__ aH, unsigned short* __restrict__ aL,
                                                const float* __restrict__ g2, const float* __restrict__ b2)
{
  const int r = blockIdx.x, t = threadIdx.x;
  __shared__ float red[4];
  float u[2];
#pragma unroll
  for (int q = 0; q < 2; ++q) {
    const int d = t + q * 256;
    const size_t gb = (size_t)r * (3 * CD) + d;
    const float sr_ = gi[gb], sz = gi[gb + CD], inn = gi[gb + 2 * CD];
    const float hn = ghn[(size_t)r * CD + d];
    const size_t hi = (size_t)r * CD + d;
    const float hp = bf_f(hH[hi]) + bf_f(hL[hi]);
    const float rr = sigm(sr_), zz = sigm(sz);
    const float nn = tanhf(inn + rr * hn);
    u[q] = (1.f - zz) * nn + zz * hp;
  }
  const float mu = blk_sum(u[0] + u[1], red) * (1.f / CD);
  const float d0 = u[0] - mu, d1 = u[1] - mu;
  const float var = blk_sum(d0 * d0 + d1 * d1, red) * (1.f / CD);
  const float inv = rsqrtf(var + CEPS);
  const float h0 = d0 * inv * g[t] + b[t];
  const float h1 = d1 * inv * g[t + 256] + b[t + 256];
  split_store(h0, &hH[(size_t)r * CD + t], &hL[(size_t)r * CD + t]);
  split_store(h1, &hH[(size_t)r * CD + t + 256], &hL[(size_t)r * CD + t + 256]);
  if (aH) {
    const float mu2 = blk_sum(h0 + h1, red) * (1.f / CD);
    const float e0 = h0 - mu2, e1 = h1 - mu2;
    const float var2 = blk_sum(e0 * e0 + e1 * e1, red) * (1.f / CD);
    const float inv2 = rsqrtf(var2 + CEPS);
    split_store(e0 * inv2 * g2[t] + b2[t], &aH[(size_t)r * CD + t], &aL[(size_t)r * CD + t]);
    split_store(e1 * inv2 * g2[t + 256] + b2[t + 256],
                &aH[(size_t)r * CD + t + 256], &aL[(size_t)r * CD + t + 256]);
  }
}

// ---------------- MFMA flash attention, pair I/O ----------------
// 1D grid + XCD swizzle (T1): the 16 qt-blocks sharing one (head,b)'s K/V stay
// on one XCD's L2. K/V for tile j+1 prefetched into registers during tile j's
// compute (T14 async-stage split) so HBM/L2 latency hides under MFMA+softmax.
constexpr int FP = 72;
__global__ __launch_bounds__(256, 2) void flash_attn_p(const unsigned short* __restrict__ qkvH,
                                                       const unsigned short* __restrict__ qkvL,
                                                       unsigned short* __restrict__ outH,
                                                       unsigned short* __restrict__ outL)
{
  __shared__ __align__(16) unsigned short Qh[64 * FP], Ql[64 * FP];
  __shared__ __align__(16) unsigned short Kh[64 * FP], Kl[64 * FP];
  __shared__ __align__(16) unsigned short Vth[64 * FP], Vtl[64 * FP];
  __shared__ __align__(16) unsigned short Pm[64 * FP];
  const int w = xcd_swz(blockIdx.x, gridDim.x);
  const int qt = w & 15, head = (w >> 4) & 7, b = w >> 7;
  const int tid = threadIdx.x;
  const int lane = tid & 63, wave = tid >> 6;
  const int r16 = lane & 15, quad = lane >> 4;
  const size_t base = (size_t)b * CN * (3 * CD) + head * CHD;

  {
    const int r = tid >> 2, c0 = (tid & 3) << 4;
    const unsigned short* qh = qkvH + base + (size_t)(qt * 64 + r) * (3 * CD) + c0;
    const unsigned short* ql = qkvL + base + (size_t)(qt * 64 + r) * (3 * CD) + c0;
    *(uint4*)&Qh[r * FP + c0]     = *(const uint4*)qh;
    *(uint4*)&Qh[r * FP + c0 + 8] = *(const uint4*)(qh + 8);
    *(uint4*)&Ql[r * FP + c0]     = *(const uint4*)ql;
    *(uint4*)&Ql[r * FP + c0 + 8] = *(const uint4*)(ql + 8);
  }
  float m_i[4], l_i[4];
  f32x4 O[4];
  const f32x4 zero = {0.f, 0.f, 0.f, 0.f};
#pragma unroll
  for (int r = 0; r < 4; ++r) { m_i[r] = -INFINITY; l_i[r] = 0.f; }
#pragma unroll
  for (int d = 0; d < 4; ++d) O[d] = zero;

  // staging lane mappings
  const int skr = tid >> 2, skc = (tid & 3) << 4;        // K: 64 rows x 64 cols
  const int rp = (tid >> 3) << 1, c0v = (tid & 7) << 3;  // V: transposed pairs
  const unsigned short* kbH = qkvH + base + CD;
  const unsigned short* kbL = qkvL + base + CD;
  const unsigned short* vbH = qkvH + base + 2 * CD;
  const unsigned short* vbL = qkvL + base + 2 * CD;

  uint4 kh0, kh1, kl0, kl1, vxh, vyh, vxl, vyl;
  auto LOADJ = [&](int j) {
    const size_t ko = (size_t)(j * 64 + skr) * (3 * CD) + skc;
    kh0 = *(const uint4*)(kbH + ko);
    kh1 = *(const uint4*)(kbH + ko + 8);
    kl0 = *(const uint4*)(kbL + ko);
    kl1 = *(const uint4*)(kbL + ko + 8);
    const size_t vo = (size_t)(j * 64 + rp) * (3 * CD) + c0v;
    vxh = *(const uint4*)(vbH + vo);
    vyh = *(const uint4*)(vbH + vo + 3 * CD);
    vxl = *(const uint4*)(vbL + vo);
    vyl = *(const uint4*)(vbL + vo + 3 * CD);
  };

  LOADJ(0);
  for (int j = 0; j <= qt; ++j) {
    // write prefetched regs to LDS (implicit vmcnt wait on first use)
    *(uint4*)&Kh[skr * FP + skc]     = kh0;
    *(uint4*)&Kh[skr * FP + skc + 8] = kh1;
    *(uint4*)&Kl[skr * FP + skc]     = kl0;
    *(uint4*)&Kl[skr * FP + skc + 8] = kl1;
    {
      unsigned short xh[8], yh[8], xl[8], yl[8];
      *(uint4*)xh = vxh; *(uint4*)yh = vyh;
      *(uint4*)xl = vxl; *(uint4*)yl = vyl;
#pragma unroll
      for (int c = 0; c < 8; ++c) {
        const int R = c0v + c;
        const int col = rp ^ ((R >> 3) << 3);
        *(unsigned*)&Vth[R * FP + col] = (unsigned)xh[c] | ((unsigned)yh[c] << 16);
        *(unsigned*)&Vtl[R * FP + col] = (unsigned)xl[c] | ((unsigned)yl[c] << 16);
      }
    }
    __syncthreads();
    if (j < qt) LOADJ(j + 1);   // loads fly under QK^T + softmax + PV
    f32x4 S[4];
#pragma unroll
    for (int nt = 0; nt < 4; ++nt) S[nt] = zero;
#pragma unroll
    for (int kh2 = 0; kh2 < 2; ++kh2) {
      const short8 qh = *(const short8*)&Qh[(wave * 16 + r16) * FP + kh2 * 32 + quad * 8];
      const short8 ql = *(const short8*)&Ql[(wave * 16 + r16) * FP + kh2 * 32 + quad * 8];
#pragma unroll
      for (int nt = 0; nt < 4; ++nt) {
        const short8 kkh = *(const short8*)&Kh[(nt * 16 + r16) * FP + kh2 * 32 + quad * 8];
        const short8 kkl = *(const short8*)&Kl[(nt * 16 + r16) * FP + kh2 * 32 + quad * 8];
        S[nt] = __builtin_amdgcn_mfma_f32_16x16x32_bf16(qh, kkh, S[nt], 0, 0, 0);
        S[nt] = __builtin_amdgcn_mfma_f32_16x16x32_bf16(qh, kkl, S[nt], 0, 0, 0);
        S[nt] = __builtin_amdgcn_mfma_f32_16x16x32_bf16(ql, kkh, S[nt], 0, 0, 0);
      }
    }
#pragma unroll
    for (int r = 0; r < 4; ++r) {
      const int qrow = wave * 16 + quad * 4 + r;
      float s[4];
#pragma unroll
      for (int nt = 0; nt < 4; ++nt) {
        s[nt] = S[nt][r] * 0.125f;
        if (j == qt && (nt * 16 + r16) > qrow) s[nt] = -1e30f;
      }
      float rm = fmaxf(fmaxf(s[0], s[1]), fmaxf(s[2], s[3]));
#pragma unroll
      for (int o = 8; o > 0; o >>= 1) rm = fmaxf(rm, __shfl_xor(rm, o, 64));
      const float newm = fmaxf(m_i[r], rm);
      float p[4], rs = 0.f;
#pragma unroll
      for (int nt = 0; nt < 4; ++nt) { p[nt] = expf(s[nt] - newm); rs += p[nt]; }
#pragma unroll
      for (int o = 8; o > 0; o >>= 1) rs += __shfl_xor(rs, o, 64);
      const float alpha = expf(m_i[r] - newm);
      l_i[r] = l_i[r] * alpha + rs;
      m_i[r] = newm;
#pragma unroll
      for (int dt = 0; dt < 4; ++dt) O[dt][r] *= alpha;
#pragma unroll
      for (int nt = 0; nt < 4; ++nt)
        Pm[qrow * FP + nt * 16 + r16] = bf_hi(p[nt]);
    }
    __syncthreads();
#pragma unroll
    for (int kh2 = 0; kh2 < 2; ++kh2) {
      const short8 pa = *(const short8*)&Pm[(wave * 16 + r16) * FP + kh2 * 32 + quad * 8];
#pragma unroll
      for (int dt = 0; dt < 4; ++dt) {
        const int R = dt * 16 + r16;
        const int col = (kh2 * 32 + quad * 8) ^ ((R >> 3) << 3);
        const short8 vh = *(const short8*)&Vth[R * FP + col];
        const short8 vl = *(const short8*)&Vtl[R * FP + col];
        O[dt] = __builtin_amdgcn_mfma_f32_16x16x32_bf16(pa, vh, O[dt], 0, 0, 0);
        O[dt] = __builtin_amdgcn_mfma_f32_16x16x32_bf16(pa, vl, O[dt], 0, 0, 0);
      }
    }
    __syncthreads();   // LDS consumed; safe to overwrite next iteration
  }
#pragma unroll
  for (int r = 0; r < 4; ++r) {
    const float inv = 1.f / l_i[r];
    const size_t row = (size_t)b * CN + qt * 64 + wave * 16 + quad * 4 + r;
#pragma unroll
    for (int dt = 0; dt < 4; ++dt) {
      const size_t o = row * CD + head * CHD + dt * 16 + r16;
      split_store(O[dt][r] * inv, &outH[o], &outL[o]);
    }
  }
}

__global__ __launch_bounds__(256) void final_ln_p(const float* __restrict__ local,
                                                  const float* __restrict__ broad,
                                                  const float* __restrict__ g, const float* __restrict__ bb,
                                                  unsigned short* __restrict__ oh,
                                                  unsigned short* __restrict__ ol)
{
  const int r = blockIdx.x, t = threadIdx.x;
  __shared__ float red[4];
  const size_t lb = (size_t)r * CD;
  const size_t br = (size_t)(r >> 2) * CD;
  const float v0 = local[lb + t] + broad[br + t];
  const float v1 = local[lb + 256 + t] + broad[br + 256 + t];
  const float mu = blk_sum(v0 + v1, red) * (1.f / CD);
  const float d0 = v0 - mu, d1 = v1 - mu;
  const float var = blk_sum(d0 * d0 + d1 * d1, red) * (1.f / CD);
  const float inv = rsqrtf(var + CEPS);
  split_store(d0 * inv * g[t] + bb[t], &oh[lb + t], &ol[lb + t]);
  split_store(d1 * inv * g[t + 256] + bb[t + 256], &oh[lb + 256 + t], &ol[lb + 256 + t]);
}

// ---------------- launcher ----------------
extern "C" void kernel_launch(void* const* d_in, const int* in_sizes, int n_in,
                              void* d_out, int out_size, void* d_ws, size_t ws_size,
                              hipStream_t stream)
{
  (void)in_sizes; (void)n_in; (void)out_size; (void)ws_size;
  const int*   x         = (const int*)d_in[0];
  const float* emb       = (const float*)d_in[1];
  const float* pos_emb   = (const float*)d_in[2];
  const float* gru_w_ih  = (const float*)d_in[3];
  const float* gru_w_hh  = (const float*)d_in[4];
  const float* gru_b_ih  = (const float*)d_in[5];
  const float* gru_b_hh  = (const float*)d_in[6];
  const float* patch_g   = (const float*)d_in[7];
  const float* patch_b   = (const float*)d_in[8];
  const float* summ_w    = (const float*)d_in[9];
  const float* summ_b    = (const float*)d_in[10];
  const float* msg_w1    = (const float*)d_in[11];
  const float* msg_b1    = (const float*)d_in[12];
  const float* msg_w2    = (const float*)d_in[13];
  const float* msg_b2    = (const float*)d_in[14];
  const float* msg_ln_g  = (const float*)d_in[15];
  const float* msg_ln_b  = (const float*)d_in[16];
  const float* q_w       = (const float*)d_in[17];
  const float* q_b       = (const float*)d_in[18];
  const float* k_w       = (const float*)d_in[19];
  const float* k_b       = (const float*)d_in[20];
  const float* v_w       = (const float*)d_in[21];
  const float* v_b       = (const float*)d_in[22];
  const float* o_w       = (const float*)d_in[23];
  const float* o_b       = (const float*)d_in[24];
  const float* gc_w_ih   = (const float*)d_in[25];
  const float* gc_w_hh   = (const float*)d_in[26];
  const float* gc_b_ih   = (const float*)d_in[27];
  const float* gc_b_hh   = (const float*)d_in[28];
  const float* ar_ln_g   = (const float*)d_in[29];
  const float* ar_ln_b   = (const float*)d_in[30];
  const float* ar_qkv_w  = (const float*)d_in[31];
  const float* ar_qkv_b  = (const float*)d_in[32];
  const float* ar_out_w  = (const float*)d_in[33];
  const float* ar_out_b  = (const float*)d_in[34];
  const float* broad_w   = (const float*)d_in[35];
  const float* broad_b   = (const float*)d_in[36];
  const float* ln_g      = (const float*)d_in[37];
  const float* ln_b      = (const float*)d_in[38];
  const float* head_w    = (const float*)d_in[39];
  float* out = (float*)d_out;

  float* ws = (float*)d_ws;
  float* WL    = ws + OFF_LOCAL;
  float* X4    = ws + OFF_X4;
  float* GI    = X4;
  float* GHN   = X4 + (size_t)ROWS * 1536;
  float* WBR   = ws + OFF_MS;
  float* Wbias5 = ws + OFF_BIAS;
  unsigned short* WTh = (unsigned short*)(ws + OFF_WT);
  unsigned short* WTl = WTh + TOT_W;
  unsigned short* WhH = (unsigned short*)(ws + OFF_HP);
  unsigned short* WhL = WhH + PN;
  unsigned short* MsH = (unsigned short*)(ws + OFF_MS);
  unsigned short* MsL = MsH + PN;
  unsigned short* pAH = (unsigned short*)(ws + OFF_A);
  unsigned short* pAL = pAH + PN;
  unsigned short* pBH = (unsigned short*)(ws + OFF_B);
  unsigned short* pBL = pBH + PN;
  unsigned short* QkH = (unsigned short*)X4;
  unsigned short* QkL = QkH + (size_t)ROWS * 1536;
  unsigned short* FnH = (unsigned short*)X4;
  unsigned short* FnL = FnH + (size_t)TROWS * CD;

  const int EW = ROWS * CD / 256;
  const float inv_sqrt_d = 0.04419417382415922f;

  auto TR = [&](const float* in, size_t off, int K, int N, int ldk, int ko) {
    transpose_split<<<dim3(N / 32, K / 32), 256, 0, stream>>>(in, WTh + off, WTl + off, K, N, ldk, ko);
  };
  TR(gru_w_ih, T_GRU_IH, 512, 1536, 512, 0);
  TR(gru_w_hh, T_GRU_HH, 512, 1536, 512, 0);
  TR(summ_w,   T_SUMM,   512, 512,  512, 0);
  TR(msg_w1,                      T_FUSE,           512, 512, 512, 0);
  TR(msg_w1 + (size_t)512 * 512,  T_FUSE + 262144,  512, 512, 512, 0);
  TR(q_w,                         T_FUSE + 524288,  512, 512, 512, 0);
  TR(k_w,                         T_FUSE + 786432,  512, 512, 512, 0);
  TR(v_w,                         T_FUSE + 1048576, 512, 512, 512, 0);
  TR(msg_w2,   T_MSG2,   512, 512,  512, 0);
  TR(o_w, T_OW, 512, 512, 512, 0);
  TR(gc_w_ih,                       T_GCAB, 512, 1536, 1024, 0);
  TR(gc_w_ih + (size_t)512 * 1536,  T_GCAB, 512, 1536, 1024, 512);
  TR(gc_w_hh,  T_GC_HH,  512, 1536, 512, 0);
  TR(ar_qkv_w, T_AR_QKV, 512, 1536, 512, 0);
  TR(ar_out_w, T_AR_OUT, 512, 512,  512, 0);
  TR(broad_w,  T_BROAD,  512, 512,  512, 0);
  TR(head_w,   T_HEAD,   512, 256,  512, 0);
  concat_bias5<<<10, 256, 0, stream>>>(msg_b1, q_b, k_b, v_b, Wbias5);

  // big weight GEMM (2-product)
  auto G3 = [&](const unsigned short* AH_, const unsigned short* AL_, int lda_,
                size_t toff, int ldb_, const float* bias_, float* Cf_, int ldc_, float* Cf2_,
                unsigned short* CHp_, unsigned short* CLp_, int ldcp_,
                int K_, int flags_, int gx, int gy) {
    gemm_bf3<false><<<dim3(gx, gy), 256, 0, stream>>>(
        AH_, AL_, AH_, AL_, K_, lda_, WTh + toff, WTl + toff, ldb_, bias_, 1.f,
        Cf_, ldc_, Cf2_, CHp_, CLp_, ldcp_, K_, flags_, 0, 0, 0);
  };
  // small weight GEMM (64x128, 2-product)
  auto G3S = [&](const unsigned short* AH_, const unsigned short* AL_, int lda_,
                 size_t toff, const float* bias_, float* Cf_, int ldc_,
                 unsigned short* CHp_, unsigned short* CLp_, int ldcp_,
                 int flags_, int gx, int gy) {
    gemm_bf3s<<<dim3(gx, gy), 256, 0, stream>>>(
        AH_, AL_, lda_, WTh + toff, 512, bias_,
        Cf_, ldc_, CHp_, CLp_, ldcp_, 512, flags_);
  };

  // ---- patch GRU over P=4 steps ----
  zero_k<<<EW, 256, 0, stream>>>(ws + OFF_HP);
  for (int t = 0; t < CP; ++t) {
    embed_p<<<EW, 256, 0, stream>>>(x, emb, pos_emb, pAH, pAL, t);
    G3(pAH, pAL, 512, T_GRU_IH, 512, gru_b_ih, GI, 1536, nullptr,
       nullptr, nullptr, 0, 512, F_WR_F32, 12, 64);
    G3(WhH, WhL, 512, T_GRU_HH, 512, gru_b_hh, GI, 1536, GHN,
       nullptr, nullptr, 0, 512, F_SPLIT, 12, 64);
    gru_point_p<<<EW, 256, 0, stream>>>(GI, GHN, WhH, WhL, WL, t);
  }
  ln_rows<<<TROWS, 256, 0, stream>>>(WL, WL, patch_g, patch_b);
  mean_pool_p<<<EW, 256, 0, stream>>>(WL, pAH, pAL);
  G3S(pAH, pAL, 512, T_SUMM, summ_b, nullptr, 0, WhH, WhL, 512, F_WR_PAIR, 4, 128);

  // ---- rounds ----
  for (int rnd = 0; rnd < 6; ++rnd) {
    G3(WhH, WhL, 512, T_FUSE, 512, Wbias5, X4, 2560, nullptr,
       nullptr, nullptr, 0, 512, F_WR_F32, 20, 64);
    msg_gelu_p<<<EW, 256, 0, stream>>>(X4, pBH, pBL);
    G3S(pBH, pBL, 512, T_MSG2, msg_b2, nullptr, 0, MsH, MsL, 512, F_WR_PAIR, 4, 128);
    rotary2_p<<<ROWS, 256, 0, stream>>>(X4, pAH, pAL, pBH, pBL);
    // scores (3-product, lower-triangular 128-tiles) -> X4 cols 0..1023
    gemm_bf3<true><<<dim3(36, 1, CB), 256, 0, stream>>>(
        pAH, pAL, pAH, pAL, 512, 512, pBH, pBL, 512, nullptr, inv_sqrt_d,
        X4, 2560, nullptr, nullptr, nullptr, 0, 512, F_WR_F32 | F_TRI,
        (long long)CN * CD, (long long)CN * CD, (long long)CN * 2560);
    topk_attn<<<ROWS / 4, 256, 0, stream>>>(X4, pAH, pAL);
    G3S(pAH, pAL, 512, T_OW, o_b, nullptr, 0, pBH, pBL, 512, F_WR_PAIR, 4, 128);
    gemm_bf3<false><<<dim3(12, 64), 256, 0, stream>>>(
        MsH, MsL, pBH, pBL, 512, 512, WTh + T_GCAB, WTl + T_GCAB, 1024, gc_b_ih, 1.f,
        GI, 1536, nullptr, nullptr, nullptr, 0, 1024, F_WR_F32, 0, 0, 0);
    G3(WhH, WhL, 512, T_GC_HH, 512, gc_b_hh, GI, 1536, GHN,
       nullptr, nullptr, 0, 512, F_SPLIT, 12, 64);
    if ((rnd & 1) == 1) {
      gru_ln_p<<<ROWS, 256, 0, stream>>>(GI, GHN, WhH, WhL, msg_ln_g, msg_ln_b,
                                         pAH, pAL, ar_ln_g, ar_ln_b);
      G3(pAH, pAL, 512, T_AR_QKV, 512, ar_qkv_b, nullptr, 0, nullptr,
         QkH, QkL, 1536, 512, F_WR_PAIR, 12, 64);
      flash_attn_p<<<dim3(16 * CH * CB), 256, 0, stream>>>(QkH, QkL, pBH, pBL);
      G3S(pBH, pBL, 512, T_AR_OUT, ar_out_b, nullptr, 0, WhH, WhL, 512,
          F_ACC_PAIR | F_WR_PAIR, 4, 128);
    } else {
      gru_ln_p<<<ROWS, 256, 0, stream>>>(GI, GHN, WhH, WhL, msg_ln_g, msg_ln_b,
                                         nullptr, nullptr, nullptr, nullptr);
    }
  }

  // ---- head ----
  G3S(WhH, WhL, 512, T_BROAD, broad_b, WBR, 512, nullptr, nullptr, 0, F_WR_F32, 4, 128);
  final_ln_p<<<TROWS, 256, 0, stream>>>(WL, WBR, ln_g, ln_b, FnH, FnL);
  G3S(FnH, FnL, 512, T_HEAD, nullptr, out, CV, nullptr, nullptr, 0, F_WR_F32, 2, 512);
}